// Round 10
// baseline (908.333 us; speedup 1.0000x reference)
//
#include <hip/hip_runtime.h>
#include <hip/hip_bf16.h>

// DeepPoly MLP verifier (784->2048x4->10).
// Round 16 RESUBMIT (previous attempt hit an infra failure, no data).
// r15 (XCD swizzle, best 829us) + r14's asm-interleaved inner tile.
// r14's 127us regression decomposed as: FETCH 139->201MB blowup
// (= ~25-30us of extra staging stall) from re-phased iterations evicting
// panels across L2s -- NOT the interleave itself. r15's swizzle pins the
// per-XCD working set to ~320KB << 4MB L2, removing that mechanism; this
// round tests the overlap schedule with locality controlled.
// Inner tile: asm ds_read_b128 (unsinkable) + counted lgkm waits:
//   B+A0+A1 -> lgkm(2) -> A2 -> MT0 -> lgkm(2) -> A3 -> MT1
//   -> lgkm(2) -> MT2 -> lgkm(0) -> MT3
// Tail per iter = r11's BAR/STAGE/vmcnt(8|6)/BAR depth-2 induction.
// Conflict-free LDS swizzle ((row>>1)&3) + T5 setprio retained.

#define MEAN_C 0.1307f
#define STD_C  0.3081f

// ---- workspace offsets (floats), total ~108.2 MB ----
#define OFF_X0     0u
#define OFF_X1     2048u
#define OFF_L0     4096u       // 896 used (zero-padded)
#define OFF_H0     5120u
#define OFF_WL     6144u       // 4*2048 (rec j at +j*2048)
#define OFF_WH     14336u
#define OFF_BHR    22528u
#define OFF_BOXA   30720u      // 4096
#define OFF_BOXB   34816u
#define OFF_BIASA  38912u      // 4096
#define OFF_BIASB  43008u
#define OFF_B20    47104u      // 32
#define OFF_W0TH   47136u      // f16 [896][2048]  = 917504 float-slots
#define OFF_W0TL   964640u
#define OFF_W1TH   1882144u    // f16 [2048][2048] = 2097152 float-slots
#define OFF_W1TL   3979296u
#define OFF_W2TH   6076448u
#define OFF_W2TL   8173600u
#define OFF_AH0    10270752u   // f16 [4096][2048] = 4194304 float-slots
#define OFF_AL0    14465056u
#define OFF_AH1    18659360u
#define OFF_AL1    22853664u
// PP split-K partials alias into AH1 (free during layer 4): 4 x 327680 floats
#define OFF_PPA    18659360u
#define OFF_PPB    18987040u
#define OFF_PPC    19314720u
#define OFF_PPD    19642400u
// end 27047968 floats

typedef _Float16 half8 __attribute__((ext_vector_type(8)));
typedef float floatx4 __attribute__((ext_vector_type(4)));

__device__ __forceinline__ void gl2lds16(const void* g, void* l) {
    __builtin_amdgcn_global_load_lds(
        (const __attribute__((address_space(1))) unsigned int*)g,
        (__attribute__((address_space(3))) unsigned int*)l, 16, 0, 0);
}

__device__ __forceinline__ float blockReduce256(float v) {
    #pragma unroll
    for (int o = 32; o > 0; o >>= 1) v += __shfl_down(v, o, 64);
    __shared__ float sred[4];
    int w = threadIdx.x >> 6;
    if ((threadIdx.x & 63) == 0) sred[w] = v;
    __syncthreads();
    float r = 0.f;
    if (threadIdx.x == 0) r = sred[0] + sred[1] + sred[2] + sred[3];
    return r;
}

__device__ __forceinline__ float2 blockReduce256x2(float a, float b) {
    #pragma unroll
    for (int o = 32; o > 0; o >>= 1) {
        a += __shfl_down(a, o, 64);
        b += __shfl_down(b, o, 64);
    }
    __shared__ float sa[4], sb[4];
    int w = threadIdx.x >> 6;
    if ((threadIdx.x & 63) == 0) { sa[w] = a; sb[w] = b; }
    __syncthreads();
    float2 r = {0.f, 0.f};
    if (threadIdx.x == 0) {
        r.x = sa[0] + sa[1] + sa[2] + sa[3];
        r.y = sb[0] + sb[1] + sb[2] + sb[3];
    }
    return r;
}

// DeepPoly relu relaxation from bounds (h,l).
__device__ __forceinline__ void relu_rec_calc(float h, float l,
                                              float& vwl, float& vwh, float& vbh) {
    if (h <= 0.f)      { vwl = 0.f; vwh = 0.f; vbh = 0.f; }
    else if (l >= 0.f) { vwl = 1.f; vwh = 1.f; vbh = 0.f; }
    else {
        float d = h - l;
        vwh = h / d;
        vbh = -(l * h) / d;
        vwl = (l * l > h * h) ? 0.f : 1.f;
    }
}

__global__ void k_norm(const float* __restrict__ x, const float* __restrict__ lo,
                       const float* __restrict__ hi, float* __restrict__ ws) {
    int i = blockIdx.x * blockDim.x + threadIdx.x;
    if (i < 784) {
        ws[OFF_X0 + i] = (x[i]  - MEAN_C) / STD_C;
        ws[OFF_L0 + i] = (lo[i] - MEAN_C) / STD_C;
        ws[OFF_H0 + i] = (hi[i] - MEAN_C) / STD_C;
    } else if (i < 896) {
        ws[OFF_L0 + i] = 0.f;
        ws[OFF_H0 + i] = 0.f;
    }
}

// Layer-0 interval matvec + forward matvec fused.
__global__ void k_fboxes0(const float* __restrict__ W0, const float* __restrict__ b0,
                          const float* __restrict__ x0,
                          const float* __restrict__ lo0, const float* __restrict__ hi0,
                          float* __restrict__ box, float* __restrict__ xout) {
    int r = blockIdx.x;
    int srow = r & 2047;
    int is_high = r < 2048;
    const float* Wr = W0 + (size_t)srow * 784;
    float acc = 0.f, accx = 0.f;
    for (int c = threadIdx.x; c < 784; c += 256) {
        float m = Wr[c];
        if (is_high) acc += (m < 0.f) ? m * lo0[c] : m * hi0[c];
        else         acc += (m < 0.f) ? m * hi0[c] : m * lo0[c];
        accx += m * x0[c];
    }
    float2 rr = blockReduce256x2(acc, accx);
    if (threadIdx.x == 0) {
        box[r] = rr.x + b0[srow];
        if (is_high) xout[r] = rr.y + b0[r];
    }
}

// First backsub step of layer i, with INLINE relu-record computation from
// (boxPrev, biasPrev): T_{i-1}(W_i) stacked (4096 rows) -> f16 hi/lo A;
// bias = bv_i + (bhr dot + T@b_{i-1}); block 0 materializes rec arrays;
// thread 0 zeroes boxOut[row]; rows<2048 also compute y = W_i@relu(x)+bv_i.
__global__ __launch_bounds__(256) void k_relu_split(
        const float* __restrict__ Wi, const float* __restrict__ xin,
        const float* __restrict__ boxPrev, const float* __restrict__ biasPrev,
        float* __restrict__ recWL, float* __restrict__ recWH, float* __restrict__ recBH,
        const float* __restrict__ bj, const float* __restrict__ bvi,
        float* __restrict__ bias, float* __restrict__ boxOut,
        float* __restrict__ xout,
        _Float16* __restrict__ Ahi, _Float16* __restrict__ Alo) {
    int row = blockIdx.x;
    int is_high = row < 2048;
    int srow = row & 2047;
    const float* src = Wi + (size_t)srow * 2048;
    int c0 = threadIdx.x * 8;
    float mv[8], bxh[8], bxl[8], abj[8], ax[8];
    *(float4*)&mv[0]  = *(const float4*)(src + c0);
    *(float4*)&mv[4]  = *(const float4*)(src + c0 + 4);
    *(float4*)&bxh[0] = *(const float4*)(boxPrev + c0);
    *(float4*)&bxh[4] = *(const float4*)(boxPrev + c0 + 4);
    *(float4*)&bxl[0] = *(const float4*)(boxPrev + 2048 + c0);
    *(float4*)&bxl[4] = *(const float4*)(boxPrev + 2048 + c0 + 4);
    *(float4*)&abj[0] = *(const float4*)(bj + c0);
    *(float4*)&abj[4] = *(const float4*)(bj + c0 + 4);
    *(float4*)&ax[0]  = *(const float4*)(xin + c0);
    *(float4*)&ax[4]  = *(const float4*)(xin + c0 + 4);
    if (biasPrev) {
        float ph[8], pl[8];
        *(float4*)&ph[0] = *(const float4*)(biasPrev + c0);
        *(float4*)&ph[4] = *(const float4*)(biasPrev + c0 + 4);
        *(float4*)&pl[0] = *(const float4*)(biasPrev + 2048 + c0);
        *(float4*)&pl[4] = *(const float4*)(biasPrev + 2048 + c0 + 4);
        #pragma unroll
        for (int e = 0; e < 8; e++) { bxh[e] += ph[e]; bxl[e] += pl[e]; }
    }
    float acc = 0.f, accx = 0.f;
    float rl[8], rh[8], rb[8];
    half8 hi, lo;
    #pragma unroll
    for (int e = 0; e < 8; e++) {
        relu_rec_calc(bxh[e], bxl[e], rl[e], rh[e], rb[e]);
        float m = mv[e];
        float t, bt;
        if (is_high) { t = (m > 0.f) ? m * rh[e] : m * rl[e]; bt = fmaxf(m, 0.f) * rb[e]; }
        else         { t = (m > 0.f) ? m * rl[e] : m * rh[e]; bt = fminf(m, 0.f) * rb[e]; }
        acc += bt + t * abj[e];
        accx += m * fmaxf(ax[e], 0.f);
        _Float16 h = (_Float16)t;
        hi[e] = h;
        lo[e] = (_Float16)(t - (float)h);
    }
    *(half8*)(Ahi + (size_t)row * 2048 + c0) = hi;
    *(half8*)(Alo + (size_t)row * 2048 + c0) = lo;
    if (row == 0) {   // materialize rec arrays for later consumers
        *(float4*)(recWL + c0) = *(float4*)&rl[0];
        *(float4*)(recWL + c0 + 4) = *(float4*)&rl[4];
        *(float4*)(recWH + c0) = *(float4*)&rh[0];
        *(float4*)(recWH + c0 + 4) = *(float4*)&rh[4];
        *(float4*)(recBH + c0) = *(float4*)&rb[0];
        *(float4*)(recBH + c0 + 4) = *(float4*)&rb[4];
    }
    float2 rr = blockReduce256x2(acc, accx);
    if (threadIdx.x == 0) {
        bias[row] = bvi[srow] + rr.x;
        boxOut[row] = 0.f;
        if (is_high) xout[row] = rr.y + bvi[row];
    }
}

// Transpose + f16 hi/lo split: Wt[n][k] = W[k][n]; pad n in [NC,NP) with 0.
__global__ void k_transpose_split(const float* __restrict__ W, int NC,
                                  _Float16* __restrict__ Thi,
                                  _Float16* __restrict__ Tlo) {
    __shared__ float s[32][33];
    int c = threadIdx.x & 31;
    int r = threadIdx.x >> 5;
    #pragma unroll
    for (int rr = 0; rr < 4; rr++) {
        int k = blockIdx.y * 32 + r + rr * 8;
        int n = blockIdx.x * 32 + c;
        float v = (n < NC) ? W[(size_t)k * NC + n] : 0.f;
        s[c][r + rr * 8] = v;
    }
    __syncthreads();
    #pragma unroll
    for (int rr = 0; rr < 4; rr++) {
        int nl = r + rr * 8;
        float v = s[nl][c];
        _Float16 h = (_Float16)v;
        size_t o = (size_t)(blockIdx.x * 32 + nl) * 2048 + blockIdx.y * 32 + c;
        Thi[o] = h;
        Tlo[o] = (_Float16)(v - (float)h);
    }
}

// asm ds_read_b128: unsinkable, ordered; address is 32-bit LDS offset.
#define DSR(dst, p)                                                          \
    asm volatile("ds_read_b128 %0, %1" : "=v"(dst)                           \
        : "v"((unsigned)(unsigned long long)                                 \
              (const __attribute__((address_space(3))) _Float16*)(p)))

// C[4096,NP] = (Ah+Al) @ (Bh+Bl)^T, 3 f16 products. BM=128, BN=NT*32,
// BK=32; 256 threads. Depth-2 counted-vmcnt pipeline (r9) + T5 setprio
// (r11) + XCD swizzle (r15) + asm-interleaved inner tile (r16).
// EPI 0: relu-backsub epilogue (emit next Ah/Al + bias atomics).
// EPI 1: interval-matvec epilogue (atomics into pre-zeroed BOX).
template<int NT, int EPI>
__global__ __launch_bounds__(256, 2) void k_gemm(
        const _Float16* __restrict__ Ah, const _Float16* __restrict__ Al,
        const _Float16* __restrict__ Bh, const _Float16* __restrict__ Bl,
        const float* __restrict__ wl, const float* __restrict__ wh,
        const float* __restrict__ bhr, const float* __restrict__ bj,
        float* __restrict__ bias,
        _Float16* __restrict__ oAh, _Float16* __restrict__ oAl,
        const float* __restrict__ lo0, const float* __restrict__ hi0,
        float* __restrict__ box) {
    __shared__ _Float16 sAh[2][128 * 32], sAl[2][128 * 32];
    __shared__ _Float16 sBh[2][NT * 32 * 32], sBl[2][NT * 32 * 32];
    int tid = threadIdx.x;

    // XCD-aware swizzle: nwg (512 or 448) is divisible by 8 -> bijective.
    int gx = gridDim.x;
    int bid = blockIdx.y * gx + blockIdx.x;
    int cpx = (gx * gridDim.y) >> 3;
    int l   = (bid & 7) * cpx + (bid >> 3);
    int bx  = l % gx;
    int by  = l / gx;
    int row0 = by * 128, col0 = bx * (NT * 32);

    int cr = tid >> 2;
    int q  = (tid & 3) ^ ((cr >> 1) & 3);   // bank swizzle at fetch (keyed on row>>1)
    const _Float16* gAh0 = Ah + (size_t)(row0 + cr) * 2048 + q * 8;
    const _Float16* gAh1 = gAh0 + (size_t)64 * 2048;
    const _Float16* gAl0 = Al + (size_t)(row0 + cr) * 2048 + q * 8;
    const _Float16* gAl1 = gAl0 + (size_t)64 * 2048;
    const _Float16* gBh0 = Bh + (size_t)(col0 + cr) * 2048 + q * 8;
    const _Float16* gBl0 = Bl + (size_t)(col0 + cr) * 2048 + q * 8;
    const _Float16* gBh1 = gBh0 + (size_t)64 * 2048;   // NT==4 only
    const _Float16* gBl1 = gBl0 + (size_t)64 * 2048;
    int loff = tid * 8;

    int lane = tid & 63, wv = tid >> 6;
    int wm = wv & 1, wn = wv >> 1;
    int l15 = lane & 15, lq = lane >> 4;
    int soff = (lq ^ ((l15 >> 1) & 3)) * 8;  // matches write-side swizzle
    int arow = wm * 64 + l15;
    int brow = wn * (NT * 16) + l15;

    floatx4 acc[4][NT];
    floatx4 z = {0.f, 0.f, 0.f, 0.f};
    #pragma unroll
    for (int i = 0; i < 4; i++)
        #pragma unroll
        for (int j = 0; j < NT; j++) acc[i][j] = z;

    // per-wave loads per K-tile: NT==4 -> 8, NT==2 -> 6
    auto STAGE = [&](int b, int k0) {
        gl2lds16(gAh0 + k0, &sAh[b][loff]);
        gl2lds16(gAh1 + k0, &sAh[b][loff + 2048]);
        gl2lds16(gAl0 + k0, &sAl[b][loff]);
        gl2lds16(gAl1 + k0, &sAl[b][loff + 2048]);
        gl2lds16(gBh0 + k0, &sBh[b][loff]);
        gl2lds16(gBl0 + k0, &sBl[b][loff]);
        if (NT == 4) {
            gl2lds16(gBh1 + k0, &sBh[b][loff + 2048]);
            gl2lds16(gBl1 + k0, &sBl[b][loff + 2048]);
        }
    };

#define MT_CLUSTER(MT_, AH_, AL_)                                            \
    {   _Pragma("unroll")                                                    \
        for (int nt = 0; nt < NT; nt++) {                                    \
            acc[MT_][nt] = __builtin_amdgcn_mfma_f32_16x16x32_f16(AH_, bh[nt], acc[MT_][nt], 0, 0, 0); \
            acc[MT_][nt] = __builtin_amdgcn_mfma_f32_16x16x32_f16(AL_, bh[nt], acc[MT_][nt], 0, 0, 0); \
            acc[MT_][nt] = __builtin_amdgcn_mfma_f32_16x16x32_f16(AH_, bl[nt], acc[MT_][nt], 0, 0, 0); \
        }                                                                    \
    }

    STAGE(0, 0);
    STAGE(1, 32);
    if constexpr (NT == 4) asm volatile("s_waitcnt vmcnt(8)" ::: "memory");
    else                   asm volatile("s_waitcnt vmcnt(6)" ::: "memory");
    __builtin_amdgcn_s_barrier();
    __builtin_amdgcn_sched_barrier(0);

    for (int t = 0; t < 64; ++t) {
        int cur = t & 1;
        half8 bh[NT], bl[NT], a0h, a0l, a1h, a1l, a2h, a2l, a3h, a3l;
        // issue B (2NT) + A0 + A1 : ordered, unsinkable
        #pragma unroll
        for (int nt = 0; nt < NT; nt++) {
            DSR(bh[nt], &sBh[cur][(brow + nt * 16) * 32 + soff]);
            DSR(bl[nt], &sBl[cur][(brow + nt * 16) * 32 + soff]);
        }
        DSR(a0h, &sAh[cur][(arow +  0) * 32 + soff]);
        DSR(a0l, &sAl[cur][(arow +  0) * 32 + soff]);
        DSR(a1h, &sAh[cur][(arow + 16) * 32 + soff]);
        DSR(a1l, &sAl[cur][(arow + 16) * 32 + soff]);
        asm volatile("s_waitcnt lgkmcnt(2)" ::: "memory");  // B+A0 done
        __builtin_amdgcn_sched_barrier(0);
        __builtin_amdgcn_s_setprio(1);
        DSR(a2h, &sAh[cur][(arow + 32) * 32 + soff]);       // fly under MT0
        DSR(a2l, &sAl[cur][(arow + 32) * 32 + soff]);
        MT_CLUSTER(0, a0h, a0l);
        asm volatile("s_waitcnt lgkmcnt(2)" ::: "memory");  // A1 done
        __builtin_amdgcn_sched_barrier(0);
        DSR(a3h, &sAh[cur][(arow + 48) * 32 + soff]);       // fly under MT1
        DSR(a3l, &sAl[cur][(arow + 48) * 32 + soff]);
        MT_CLUSTER(1, a1h, a1l);
        asm volatile("s_waitcnt lgkmcnt(2)" ::: "memory");  // A2 done
        __builtin_amdgcn_sched_barrier(0);
        MT_CLUSTER(2, a2h, a2l);
        asm volatile("s_waitcnt lgkmcnt(0)" ::: "memory");  // A3 done
        __builtin_amdgcn_sched_barrier(0);
        MT_CLUSTER(3, a3h, a3l);
        __builtin_amdgcn_s_setprio(0);
        // lgkm queue empty here (last wait was 0); reads of buf[cur] retired
        __builtin_amdgcn_s_barrier();
        __builtin_amdgcn_sched_barrier(0);
        if (t < 62) STAGE(cur, (t + 2) * 32);   // overwrite buf[cur] for t+2
        if (t < 63) {
            if (t < 62) {   // wait tile t+1 only; t+2's loads stay in flight
                if constexpr (NT == 4) asm volatile("s_waitcnt vmcnt(8)" ::: "memory");
                else                   asm volatile("s_waitcnt vmcnt(6)" ::: "memory");
            } else {        // pipeline drain before the final tile
                asm volatile("s_waitcnt vmcnt(0)" ::: "memory");
            }
            __builtin_amdgcn_s_barrier();
            __builtin_amdgcn_sched_barrier(0);
        }
    }
#undef MT_CLUSTER

    // C/D layout: col = lane&15, row = (lane>>4)*4 + reg
    int is_high = row0 < 2048;
    float bsum[4][4];
    #pragma unroll
    for (int mt = 0; mt < 4; mt++)
        #pragma unroll
        for (int r = 0; r < 4; r++) bsum[mt][r] = 0.f;

    #pragma unroll
    for (int nt = 0; nt < NT; nt++) {
        int gc = col0 + wn * (NT * 16) + nt * 16 + l15;
        if (EPI == 0) {
            float cwl = wl[gc], cwh = wh[gc], cbh = bhr[gc], cbj = bj[gc];
            #pragma unroll
            for (int mt = 0; mt < 4; mt++) {
                #pragma unroll
                for (int r = 0; r < 4; r++) {
                    float m = acc[mt][nt][r];
                    float t, bt;
                    if (is_high) { t = (m > 0.f) ? m * cwh : m * cwl; bt = fmaxf(m, 0.f) * cbh; }
                    else         { t = (m > 0.f) ? m * cwl : m * cwh; bt = fminf(m, 0.f) * cbh; }
                    bsum[mt][r] += bt + t * cbj;
                    int grow = row0 + wm * 64 + mt * 16 + lq * 4 + r;
                    size_t o = (size_t)grow * 2048 + gc;
                    _Float16 h = (_Float16)t;
                    oAh[o] = h;
                    oAl[o] = (_Float16)(t - (float)h);
                }
            }
        } else {
            float clo = lo0[gc], chi = hi0[gc];
            #pragma unroll
            for (int mt = 0; mt < 4; mt++) {
                #pragma unroll
                for (int r = 0; r < 4; r++) {
                    float m = acc[mt][nt][r];
                    float contrib;
                    if (is_high) contrib = (m < 0.f) ? m * clo : m * chi;
                    else         contrib = (m < 0.f) ? m * chi : m * clo;
                    bsum[mt][r] += contrib;
                }
            }
        }
    }
    #pragma unroll
    for (int mt = 0; mt < 4; mt++) {
        #pragma unroll
        for (int r = 0; r < 4; r++) {
            float v = bsum[mt][r];
            v += __shfl_xor(v, 1);
            v += __shfl_xor(v, 2);
            v += __shfl_xor(v, 4);
            v += __shfl_xor(v, 8);
            if (l15 == 0) {
                int grow = row0 + wm * 64 + mt * 16 + lq * 4 + r;
                if (EPI == 0) atomicAdd(&bias[grow], v);
                else          atomicAdd(&box[grow], v);
            }
        }
    }
}

// Rec3 capture only (layer-4 consumers read materialized arrays).
__global__ void k_relu_rec(const float* __restrict__ box, const float* __restrict__ bias,
                           float* __restrict__ wl, float* __restrict__ wh,
                           float* __restrict__ bhr) {
    int i = blockIdx.x * blockDim.x + threadIdx.x;
    float h = box[i] + bias[i];
    float l = box[2048 + i] + bias[2048 + i];
    float vwl, vwh, vbh;
    relu_rec_calc(h, l, vwl, vwh, vbh);
    wl[i] = vwl; wh[i] = vwh; bhr[i] = vbh;
}

// Layer-4 fused: reduce prev partials (or W4 bcast) + relu-backsub transform
// in prologue, then split-K skinny GEMM. Rows 0..9 high, 10..19 low.
__global__ __launch_bounds__(256) void k_skinny2(
        const float* __restrict__ src, int bcast,
        const float* __restrict__ wl, const float* __restrict__ wh,
        const float* __restrict__ W, int N, float* __restrict__ Ppart) {
    __shared__ float sA[20 * 256];
    __shared__ float sRed[20 * 128];
    int ky = blockIdx.y, k0 = ky * 256;
    int tid = threadIdx.x;
    for (int idx = tid; idx < 20 * 256; idx += 256) {
        int r = idx >> 8, c = idx & 255;
        int gc = k0 + c;
        float m;
        if (bcast) m = src[(size_t)(r % 10) * 2048 + gc];
        else {
            m = 0.f;
            #pragma unroll
            for (int p = 0; p < 8; p++)
                m += src[(size_t)p * 40960 + (size_t)r * 2048 + gc];
        }
        float t = (r < 10) ? ((m > 0.f) ? m * wh[gc] : m * wl[gc])
                           : ((m > 0.f) ? m * wl[gc] : m * wh[gc]);
        sA[idx] = t;
    }
    __syncthreads();
    int c = blockIdx.x * 128 + (tid & 127);
    int kh = tid >> 7;
    float acc[20];
    #pragma unroll
    for (int r = 0; r < 20; r++) acc[r] = 0.f;
    if (c < N) {
        const float* Wp = W + (size_t)(k0 + kh * 128) * N + c;
        for (int kk = 0; kk < 128; kk++) {
            float w = Wp[(size_t)kk * N];
            #pragma unroll
            for (int r = 0; r < 20; r++) acc[r] += sA[r * 256 + kh * 128 + kk] * w;
        }
    }
    if (kh == 1 && c < N) {
        #pragma unroll
        for (int r = 0; r < 20; r++) sRed[r * 128 + (tid & 127)] = acc[r];
    }
    __syncthreads();
    if (kh == 0 && c < N) {
        #pragma unroll
        for (int r = 0; r < 20; r++)
            Ppart[(size_t)ky * 40960 + (size_t)r * 2048 + c] =
                acc[r] + sRed[r * 128 + (tid & 127)];
    }
}

// All four layer-4 bias dots + the forward matvec (out[0..9]) in one kernel.
__global__ void k_bias20(const float* __restrict__ W4,
                         const float* __restrict__ PPa, const float* __restrict__ PPb,
                         const float* __restrict__ PPc,
                         const float* __restrict__ WLr, const float* __restrict__ WHr,
                         const float* __restrict__ BHr,
                         const float* __restrict__ b0, const float* __restrict__ b1,
                         const float* __restrict__ b2, const float* __restrict__ b3,
                         const float* __restrict__ b4,
                         const float* __restrict__ x3,
                         float* __restrict__ bias20, float* __restrict__ out) {
    int row = blockIdx.x;
    int is_high = row < 10;
    int srow = row % 10;
    float acc = 0.f, accx = 0.f;
    for (int c = threadIdx.x; c < 2048; c += 256) {
        {   // rec3 on W4 (+ forward matvec with relu'd x3)
            float m = W4[(size_t)srow * 2048 + c];
            float wlv = WLr[3 * 2048 + c], whv = WHr[3 * 2048 + c], bhv = BHr[3 * 2048 + c];
            float t  = is_high ? ((m > 0.f) ? m * whv : m * wlv) : ((m > 0.f) ? m * wlv : m * whv);
            float bt = is_high ? fmaxf(m, 0.f) * bhv : fminf(m, 0.f) * bhv;
            acc += bt + t * b3[c];
            accx += m * fmaxf(x3[c], 0.f);
        }
        {   // rec2 on sum PPa
            float m = 0.f;
            #pragma unroll
            for (int p = 0; p < 8; p++) m += PPa[(size_t)p * 40960 + (size_t)row * 2048 + c];
            float wlv = WLr[2 * 2048 + c], whv = WHr[2 * 2048 + c], bhv = BHr[2 * 2048 + c];
            float t  = is_high ? ((m > 0.f) ? m * whv : m * wlv) : ((m > 0.f) ? m * wlv : m * whv);
            float bt = is_high ? fmaxf(m, 0.f) * bhv : fminf(m, 0.f) * bhv;
            acc += bt + t * b2[c];
        }
        {   // rec1 on sum PPb
            float m = 0.f;
            #pragma unroll
            for (int p = 0; p < 8; p++) m += PPb[(size_t)p * 40960 + (size_t)row * 2048 + c];
            float wlv = WLr[1 * 2048 + c], whv = WHr[1 * 2048 + c], bhv = BHr[1 * 2048 + c];
            float t  = is_high ? ((m > 0.f) ? m * whv : m * wlv) : ((m > 0.f) ? m * wlv : m * whv);
            float bt = is_high ? fmaxf(m, 0.f) * bhv : fminf(m, 0.f) * bhv;
            acc += bt + t * b1[c];
        }
        {   // rec0 on sum PPc
            float m = 0.f;
            #pragma unroll
            for (int p = 0; p < 8; p++) m += PPc[(size_t)p * 40960 + (size_t)row * 2048 + c];
            float wlv = WLr[c], whv = WHr[c], bhv = BHr[c];
            float t  = is_high ? ((m > 0.f) ? m * whv : m * wlv) : ((m > 0.f) ? m * wlv : m * whv);
            float bt = is_high ? fmaxf(m, 0.f) * bhv : fminf(m, 0.f) * bhv;
            acc += bt + t * b0[c];
        }
    }
    float2 rr = blockReduce256x2(acc, accx);
    if (threadIdx.x == 0) {
        bias20[row] = b4[srow] + rr.x;
        if (is_high) out[row] = b4[row] + rr.y;
    }
}

// Final layer-4 interval matvec from 8 split-K parts.
__global__ void k_fbox20(const float* __restrict__ Ppart,
                         const float* __restrict__ bias20,
                         const float* __restrict__ lo0, const float* __restrict__ hi0,
                         float* __restrict__ out) {
    int row = blockIdx.x;
    int is_high = row < 10;
    float acc = 0.f;
    for (int c = threadIdx.x; c < 784; c += 256) {
        float m = 0.f;
        #pragma unroll
        for (int p = 0; p < 8; p++)
            m += Ppart[(size_t)p * 40960 + (size_t)row * 2048 + c];
        if (is_high) acc += (m < 0.f) ? m * lo0[c] : m * hi0[c];
        else         acc += (m < 0.f) ? m * hi0[c] : m * lo0[c];
    }
    acc = blockReduce256(acc);
    if (threadIdx.x == 0) {
        float v = acc + bias20[row];
        out[is_high ? (20 + row) : row] = v;
    }
}

extern "C" void kernel_launch(void* const* d_in, const int* in_sizes, int n_in,
                              void* d_out, int out_size, void* d_ws, size_t ws_size,
                              hipStream_t stream) {
    const float* x_in  = (const float*)d_in[0];
    const float* lo_in = (const float*)d_in[1];
    const float* hi_in = (const float*)d_in[2];
    const float* W[5];
    const float* bv[5];
    for (int i = 0; i < 5; i++) {
        W[i]  = (const float*)d_in[3 + 2 * i];
        bv[i] = (const float*)d_in[4 + 2 * i];
    }
    float* ws = (float*)d_ws;
    float* out = (float*)d_out;

    float* X[2]    = {ws + OFF_X0, ws + OFF_X1};
    float* lo0     = ws + OFF_L0;
    float* hi0     = ws + OFF_H0;
    float* BOX[2]  = {ws + OFF_BOXA, ws + OFF_BOXB};
    float* BIAS[2] = {ws + OFF_BIASA, ws + OFF_BIASB};
    float* b20     = ws + OFF_B20;
    float* PPa     = ws + OFF_PPA;
    float* PPb     = ws + OFF_PPB;
    float* PPc     = ws + OFF_PPC;
    float* PPd     = ws + OFF_PPD;
    _Float16* WT_H[3] = {(_Float16*)(ws + OFF_W0TH), (_Float16*)(ws + OFF_W1TH),
                         (_Float16*)(ws + OFF_W2TH)};
    _Float16* WT_L[3] = {(_Float16*)(ws + OFF_W0TL), (_Float16*)(ws + OFF_W1TL),
                         (_Float16*)(ws + OFF_W2TL)};
    _Float16* AH[2] = {(_Float16*)(ws + OFF_AH0), (_Float16*)(ws + OFF_AH1)};
    _Float16* AL[2] = {(_Float16*)(ws + OFF_AL0), (_Float16*)(ws + OFF_AL1)};
    float* WLr = ws + OFF_WL;
    float* WHr = ws + OFF_WH;
    float* BHr = ws + OFF_BHR;

    k_norm<<<4, 256, 0, stream>>>(x_in, lo_in, hi_in, ws);
    // hoisted transposes (input-only dependencies)
    k_transpose_split<<<dim3(28, 64), 256, 0, stream>>>(W[0], 784, WT_H[0], WT_L[0]);
    k_transpose_split<<<dim3(64, 64), 256, 0, stream>>>(W[1], 2048, WT_H[1], WT_L[1]);
    k_transpose_split<<<dim3(64, 64), 256, 0, stream>>>(W[2], 2048, WT_H[2], WT_L[2]);

    // ---- layer 0 ----
    k_fboxes0<<<4096, 256, 0, stream>>>(W[0], bv[0], X[0], lo0, hi0, BOX[0], X[1]);

    // ---- layers 1..3 ----
    int xcur = 1, bprev = 0;   // BOX[bprev] = prev layer bounds; bias ping-pong
    const float* biasPrev = nullptr;
    for (int i = 1; i <= 3; i++) {
        int xnxt = xcur ^ 1;
        int bcur = bprev ^ 1;
        float* biasCur = BIAS[(i - 1) & 1];
        k_relu_split<<<4096, 256, 0, stream>>>(
            W[i], X[xcur], BOX[bprev], biasPrev,
            WLr + (i - 1) * 2048, WHr + (i - 1) * 2048, BHr + (i - 1) * 2048,
            bv[i - 1], bv[i], biasCur, BOX[bcur], X[xnxt], AH[0], AL[0]);
        int p = 0;
        for (int j = i - 1; j >= 1; j--) {
            k_gemm<4, 0><<<dim3(16, 32), 256, 0, stream>>>(
                AH[p], AL[p], WT_H[j], WT_L[j],
                WLr + (j - 1) * 2048, WHr + (j - 1) * 2048,
                BHr + (j - 1) * 2048, bv[j - 1], biasCur,
                AH[p ^ 1], AL[p ^ 1], nullptr, nullptr, nullptr);
            p ^= 1;
        }
        k_gemm<2, 1><<<dim3(14, 32), 256, 0, stream>>>(
            AH[p], AL[p], WT_H[0], WT_L[0],
            nullptr, nullptr, nullptr, nullptr, nullptr,
            nullptr, nullptr, lo0, hi0, BOX[bcur]);
        biasPrev = biasCur;
        bprev = bcur;
        xcur = xnxt;
    }
    // rec3 for the layer-4 path (BIAS[(3-1)&1] = BIAS[0])
    k_relu_rec<<<8, 256, 0, stream>>>(BOX[bprev], BIAS[0],
                                      WLr + 3 * 2048, WHr + 3 * 2048, BHr + 3 * 2048);

    // ---- layer 4: 20-row chains (split-K partial path) ----
    k_skinny2<<<dim3(16, 8), 256, 0, stream>>>(W[4], 1,
        WLr + 3 * 2048, WHr + 3 * 2048, W[3], 2048, PPa);
    k_skinny2<<<dim3(16, 8), 256, 0, stream>>>(PPa, 0,
        WLr + 2 * 2048, WHr + 2 * 2048, W[2], 2048, PPb);
    k_skinny2<<<dim3(16, 8), 256, 0, stream>>>(PPb, 0,
        WLr + 1 * 2048, WHr + 1 * 2048, W[1], 2048, PPc);
    k_skinny2<<<dim3(7, 8), 256, 0, stream>>>(PPc, 0,
        WLr, WHr, W[0], 784, PPd);
    k_bias20<<<20, 256, 0, stream>>>(W[4], PPa, PPb, PPc,
        WLr, WHr, BHr, bv[0], bv[1], bv[2], bv[3], bv[4], X[xcur], b20, out);
    k_fbox20<<<20, 256, 0, stream>>>(PPd, b20, lo0, hi0, out);
}

// Round 11
// 895.093 us; speedup vs baseline: 1.0148x; 1.0148x over previous
//
#include <hip/hip_runtime.h>
#include <hip/hip_bf16.h>

// DeepPoly MLP verifier (784->2048x4->10).
// Round 17: REVERT to r15 schedule (829us best; r16 proved the asm
// interleave intrinsically negative: FETCH re-blew 83->160MB even with
// the XCD swizzle). Single new variable: MFMA shape 16x16x32 ->
// 32x32x16. Measured ubench: 32x32 = 2495 TF vs 16x16 = 2075 TF ->
// ~17% fewer matrix-pipe cycles for identical FLOP. Same LDS layout,
// staging, byte counts, read counts, acc VGPR; only fragment shapes,
// MFMA calls, and the epilogue lane mapping change.
// C/D: col=lane&31, row=(reg&3)+8*(reg>>2)+4*(lane>>5) (m74/m101).
// A/B: row/col=lane&31, k=(lane>>5)*8+e. Bank-conflict audit: 2-way
// minimum (free) with the existing XOR swizzle (key ((l&31)>>1)&3).
// Depth-2 counted-vmcnt pipeline + T5 setprio + XCD swizzle retained.

#define MEAN_C 0.1307f
#define STD_C  0.3081f

// ---- workspace offsets (floats), total ~108.2 MB ----
#define OFF_X0     0u
#define OFF_X1     2048u
#define OFF_L0     4096u       // 896 used (zero-padded)
#define OFF_H0     5120u
#define OFF_WL     6144u       // 4*2048 (rec j at +j*2048)
#define OFF_WH     14336u
#define OFF_BHR    22528u
#define OFF_BOXA   30720u      // 4096
#define OFF_BOXB   34816u
#define OFF_BIASA  38912u      // 4096
#define OFF_BIASB  43008u
#define OFF_B20    47104u      // 32
#define OFF_W0TH   47136u      // f16 [896][2048]  = 917504 float-slots
#define OFF_W0TL   964640u
#define OFF_W1TH   1882144u    // f16 [2048][2048] = 2097152 float-slots
#define OFF_W1TL   3979296u
#define OFF_W2TH   6076448u
#define OFF_W2TL   8173600u
#define OFF_AH0    10270752u   // f16 [4096][2048] = 4194304 float-slots
#define OFF_AL0    14465056u
#define OFF_AH1    18659360u
#define OFF_AL1    22853664u
// PP split-K partials alias into AH1 (free during layer 4): 4 x 327680 floats
#define OFF_PPA    18659360u
#define OFF_PPB    18987040u
#define OFF_PPC    19314720u
#define OFF_PPD    19642400u
// end 27047968 floats

typedef _Float16 half8 __attribute__((ext_vector_type(8)));
typedef float floatx4 __attribute__((ext_vector_type(4)));
typedef float floatx16 __attribute__((ext_vector_type(16)));

__device__ __forceinline__ void gl2lds16(const void* g, void* l) {
    __builtin_amdgcn_global_load_lds(
        (const __attribute__((address_space(1))) unsigned int*)g,
        (__attribute__((address_space(3))) unsigned int*)l, 16, 0, 0);
}

__device__ __forceinline__ float blockReduce256(float v) {
    #pragma unroll
    for (int o = 32; o > 0; o >>= 1) v += __shfl_down(v, o, 64);
    __shared__ float sred[4];
    int w = threadIdx.x >> 6;
    if ((threadIdx.x & 63) == 0) sred[w] = v;
    __syncthreads();
    float r = 0.f;
    if (threadIdx.x == 0) r = sred[0] + sred[1] + sred[2] + sred[3];
    return r;
}

__device__ __forceinline__ float2 blockReduce256x2(float a, float b) {
    #pragma unroll
    for (int o = 32; o > 0; o >>= 1) {
        a += __shfl_down(a, o, 64);
        b += __shfl_down(b, o, 64);
    }
    __shared__ float sa[4], sb[4];
    int w = threadIdx.x >> 6;
    if ((threadIdx.x & 63) == 0) { sa[w] = a; sb[w] = b; }
    __syncthreads();
    float2 r = {0.f, 0.f};
    if (threadIdx.x == 0) {
        r.x = sa[0] + sa[1] + sa[2] + sa[3];
        r.y = sb[0] + sb[1] + sb[2] + sb[3];
    }
    return r;
}

// DeepPoly relu relaxation from bounds (h,l).
__device__ __forceinline__ void relu_rec_calc(float h, float l,
                                              float& vwl, float& vwh, float& vbh) {
    if (h <= 0.f)      { vwl = 0.f; vwh = 0.f; vbh = 0.f; }
    else if (l >= 0.f) { vwl = 1.f; vwh = 1.f; vbh = 0.f; }
    else {
        float d = h - l;
        vwh = h / d;
        vbh = -(l * h) / d;
        vwl = (l * l > h * h) ? 0.f : 1.f;
    }
}

__global__ void k_norm(const float* __restrict__ x, const float* __restrict__ lo,
                       const float* __restrict__ hi, float* __restrict__ ws) {
    int i = blockIdx.x * blockDim.x + threadIdx.x;
    if (i < 784) {
        ws[OFF_X0 + i] = (x[i]  - MEAN_C) / STD_C;
        ws[OFF_L0 + i] = (lo[i] - MEAN_C) / STD_C;
        ws[OFF_H0 + i] = (hi[i] - MEAN_C) / STD_C;
    } else if (i < 896) {
        ws[OFF_L0 + i] = 0.f;
        ws[OFF_H0 + i] = 0.f;
    }
}

// Layer-0 interval matvec + forward matvec fused.
__global__ void k_fboxes0(const float* __restrict__ W0, const float* __restrict__ b0,
                          const float* __restrict__ x0,
                          const float* __restrict__ lo0, const float* __restrict__ hi0,
                          float* __restrict__ box, float* __restrict__ xout) {
    int r = blockIdx.x;
    int srow = r & 2047;
    int is_high = r < 2048;
    const float* Wr = W0 + (size_t)srow * 784;
    float acc = 0.f, accx = 0.f;
    for (int c = threadIdx.x; c < 784; c += 256) {
        float m = Wr[c];
        if (is_high) acc += (m < 0.f) ? m * lo0[c] : m * hi0[c];
        else         acc += (m < 0.f) ? m * hi0[c] : m * lo0[c];
        accx += m * x0[c];
    }
    float2 rr = blockReduce256x2(acc, accx);
    if (threadIdx.x == 0) {
        box[r] = rr.x + b0[srow];
        if (is_high) xout[r] = rr.y + b0[r];
    }
}

// First backsub step of layer i, with INLINE relu-record computation from
// (boxPrev, biasPrev): T_{i-1}(W_i) stacked (4096 rows) -> f16 hi/lo A;
// bias = bv_i + (bhr dot + T@b_{i-1}); block 0 materializes rec arrays;
// thread 0 zeroes boxOut[row]; rows<2048 also compute y = W_i@relu(x)+bv_i.
__global__ __launch_bounds__(256) void k_relu_split(
        const float* __restrict__ Wi, const float* __restrict__ xin,
        const float* __restrict__ boxPrev, const float* __restrict__ biasPrev,
        float* __restrict__ recWL, float* __restrict__ recWH, float* __restrict__ recBH,
        const float* __restrict__ bj, const float* __restrict__ bvi,
        float* __restrict__ bias, float* __restrict__ boxOut,
        float* __restrict__ xout,
        _Float16* __restrict__ Ahi, _Float16* __restrict__ Alo) {
    int row = blockIdx.x;
    int is_high = row < 2048;
    int srow = row & 2047;
    const float* src = Wi + (size_t)srow * 2048;
    int c0 = threadIdx.x * 8;
    float mv[8], bxh[8], bxl[8], abj[8], ax[8];
    *(float4*)&mv[0]  = *(const float4*)(src + c0);
    *(float4*)&mv[4]  = *(const float4*)(src + c0 + 4);
    *(float4*)&bxh[0] = *(const float4*)(boxPrev + c0);
    *(float4*)&bxh[4] = *(const float4*)(boxPrev + c0 + 4);
    *(float4*)&bxl[0] = *(const float4*)(boxPrev + 2048 + c0);
    *(float4*)&bxl[4] = *(const float4*)(boxPrev + 2048 + c0 + 4);
    *(float4*)&abj[0] = *(const float4*)(bj + c0);
    *(float4*)&abj[4] = *(const float4*)(bj + c0 + 4);
    *(float4*)&ax[0]  = *(const float4*)(xin + c0);
    *(float4*)&ax[4]  = *(const float4*)(xin + c0 + 4);
    if (biasPrev) {
        float ph[8], pl[8];
        *(float4*)&ph[0] = *(const float4*)(biasPrev + c0);
        *(float4*)&ph[4] = *(const float4*)(biasPrev + c0 + 4);
        *(float4*)&pl[0] = *(const float4*)(biasPrev + 2048 + c0);
        *(float4*)&pl[4] = *(const float4*)(biasPrev + 2048 + c0 + 4);
        #pragma unroll
        for (int e = 0; e < 8; e++) { bxh[e] += ph[e]; bxl[e] += pl[e]; }
    }
    float acc = 0.f, accx = 0.f;
    float rl[8], rh[8], rb[8];
    half8 hi, lo;
    #pragma unroll
    for (int e = 0; e < 8; e++) {
        relu_rec_calc(bxh[e], bxl[e], rl[e], rh[e], rb[e]);
        float m = mv[e];
        float t, bt;
        if (is_high) { t = (m > 0.f) ? m * rh[e] : m * rl[e]; bt = fmaxf(m, 0.f) * rb[e]; }
        else         { t = (m > 0.f) ? m * rl[e] : m * rh[e]; bt = fminf(m, 0.f) * rb[e]; }
        acc += bt + t * abj[e];
        accx += m * fmaxf(ax[e], 0.f);
        _Float16 h = (_Float16)t;
        hi[e] = h;
        lo[e] = (_Float16)(t - (float)h);
    }
    *(half8*)(Ahi + (size_t)row * 2048 + c0) = hi;
    *(half8*)(Alo + (size_t)row * 2048 + c0) = lo;
    if (row == 0) {   // materialize rec arrays for later consumers
        *(float4*)(recWL + c0) = *(float4*)&rl[0];
        *(float4*)(recWL + c0 + 4) = *(float4*)&rl[4];
        *(float4*)(recWH + c0) = *(float4*)&rh[0];
        *(float4*)(recWH + c0 + 4) = *(float4*)&rh[4];
        *(float4*)(recBH + c0) = *(float4*)&rb[0];
        *(float4*)(recBH + c0 + 4) = *(float4*)&rb[4];
    }
    float2 rr = blockReduce256x2(acc, accx);
    if (threadIdx.x == 0) {
        bias[row] = bvi[srow] + rr.x;
        boxOut[row] = 0.f;
        if (is_high) xout[row] = rr.y + bvi[row];
    }
}

// Transpose + f16 hi/lo split: Wt[n][k] = W[k][n]; pad n in [NC,NP) with 0.
__global__ void k_transpose_split(const float* __restrict__ W, int NC,
                                  _Float16* __restrict__ Thi,
                                  _Float16* __restrict__ Tlo) {
    __shared__ float s[32][33];
    int c = threadIdx.x & 31;
    int r = threadIdx.x >> 5;
    #pragma unroll
    for (int rr = 0; rr < 4; rr++) {
        int k = blockIdx.y * 32 + r + rr * 8;
        int n = blockIdx.x * 32 + c;
        float v = (n < NC) ? W[(size_t)k * NC + n] : 0.f;
        s[c][r + rr * 8] = v;
    }
    __syncthreads();
    #pragma unroll
    for (int rr = 0; rr < 4; rr++) {
        int nl = r + rr * 8;
        float v = s[nl][c];
        _Float16 h = (_Float16)v;
        size_t o = (size_t)(blockIdx.x * 32 + nl) * 2048 + blockIdx.y * 32 + c;
        Thi[o] = h;
        Tlo[o] = (_Float16)(v - (float)h);
    }
}

// C[4096,NP] = (Ah+Al) @ (Bh+Bl)^T, 3 f16 products. BM=128, BN=NT*32,
// BK=32; 256 threads. r15 schedule (depth-2 counted-vmcnt, T5 setprio,
// XCD swizzle) with 32x32x16 MFMA (r17): 2x2(x NTT) tile grid per wave,
// floatx16 accumulators, same LDS layout and staging.
// EPI 0: relu-backsub epilogue (emit next Ah/Al + bias atomics).
// EPI 1: interval-matvec epilogue (atomics into pre-zeroed BOX).
template<int NT, int EPI>
__global__ __launch_bounds__(256, 2) void k_gemm(
        const _Float16* __restrict__ Ah, const _Float16* __restrict__ Al,
        const _Float16* __restrict__ Bh, const _Float16* __restrict__ Bl,
        const float* __restrict__ wl, const float* __restrict__ wh,
        const float* __restrict__ bhr, const float* __restrict__ bj,
        float* __restrict__ bias,
        _Float16* __restrict__ oAh, _Float16* __restrict__ oAl,
        const float* __restrict__ lo0, const float* __restrict__ hi0,
        float* __restrict__ box) {
    constexpr int NTT = NT / 2;   // 32-wide col tiles per wave
    __shared__ _Float16 sAh[2][128 * 32], sAl[2][128 * 32];
    __shared__ _Float16 sBh[2][NT * 32 * 32], sBl[2][NT * 32 * 32];
    int tid = threadIdx.x;

    // XCD-aware swizzle: nwg (512 or 448) is divisible by 8 -> bijective.
    int gx = gridDim.x;
    int bid = blockIdx.y * gx + blockIdx.x;
    int cpx = (gx * gridDim.y) >> 3;
    int l   = (bid & 7) * cpx + (bid >> 3);
    int bx  = l % gx;
    int by  = l / gx;
    int row0 = by * 128, col0 = bx * (NT * 32);

    int cr = tid >> 2;
    int q  = (tid & 3) ^ ((cr >> 1) & 3);   // bank swizzle at fetch (keyed on row>>1)
    const _Float16* gAh0 = Ah + (size_t)(row0 + cr) * 2048 + q * 8;
    const _Float16* gAh1 = gAh0 + (size_t)64 * 2048;
    const _Float16* gAl0 = Al + (size_t)(row0 + cr) * 2048 + q * 8;
    const _Float16* gAl1 = gAl0 + (size_t)64 * 2048;
    const _Float16* gBh0 = Bh + (size_t)(col0 + cr) * 2048 + q * 8;
    const _Float16* gBl0 = Bl + (size_t)(col0 + cr) * 2048 + q * 8;
    const _Float16* gBh1 = gBh0 + (size_t)64 * 2048;   // NT==4 only
    const _Float16* gBl1 = gBl0 + (size_t)64 * 2048;
    int loff = tid * 8;

    int lane = tid & 63, wv = tid >> 6;
    int wm = wv & 1, wn = wv >> 1;
    int l31 = lane & 31, kh = lane >> 5;    // 32x32 lane row/col + k-half
    int key = (l31 >> 1) & 3;               // read-side swizzle key
    int abase = wm * 64;
    int bbase = wn * (NTT * 32);

    floatx16 acc[2][NTT];
    #pragma unroll
    for (int i = 0; i < 2; i++)
        #pragma unroll
        for (int j = 0; j < NTT; j++)
            #pragma unroll
            for (int e = 0; e < 16; e++) acc[i][j][e] = 0.f;

    // per-wave loads per K-tile: NT==4 -> 8, NT==2 -> 6
    auto STAGE = [&](int b, int k0) {
        gl2lds16(gAh0 + k0, &sAh[b][loff]);
        gl2lds16(gAh1 + k0, &sAh[b][loff + 2048]);
        gl2lds16(gAl0 + k0, &sAl[b][loff]);
        gl2lds16(gAl1 + k0, &sAl[b][loff + 2048]);
        gl2lds16(gBh0 + k0, &sBh[b][loff]);
        gl2lds16(gBl0 + k0, &sBl[b][loff]);
        if (NT == 4) {
            gl2lds16(gBh1 + k0, &sBh[b][loff + 2048]);
            gl2lds16(gBl1 + k0, &sBl[b][loff + 2048]);
        }
    };

    STAGE(0, 0);
    STAGE(1, 32);
    if constexpr (NT == 4) asm volatile("s_waitcnt vmcnt(8)" ::: "memory");
    else                   asm volatile("s_waitcnt vmcnt(6)" ::: "memory");
    __builtin_amdgcn_s_barrier();
    __builtin_amdgcn_sched_barrier(0);

    for (int t = 0; t < 64; ++t) {
        int cur = t & 1;
        half8 bhf[NTT][2], blf[NTT][2], ahf[2][2], alf[2][2];  // [tile][kstep]
        #pragma unroll
        for (int nt2 = 0; nt2 < NTT; nt2++)
            #pragma unroll
            for (int s = 0; s < 2; s++) {
                int off = (bbase + nt2 * 32 + l31) * 32 + (((s * 2 + kh) ^ key) * 8);
                bhf[nt2][s] = *(const half8*)&sBh[cur][off];
                blf[nt2][s] = *(const half8*)&sBl[cur][off];
            }
        #pragma unroll
        for (int mt = 0; mt < 2; mt++)
            #pragma unroll
            for (int s = 0; s < 2; s++) {
                int off = (abase + mt * 32 + l31) * 32 + (((s * 2 + kh) ^ key) * 8);
                ahf[mt][s] = *(const half8*)&sAh[cur][off];
                alf[mt][s] = *(const half8*)&sAl[cur][off];
            }
        // all reads of buf[cur] retired before anyone overwrites it
        asm volatile("s_waitcnt lgkmcnt(0)" ::: "memory");
        __builtin_amdgcn_sched_barrier(0);
        __builtin_amdgcn_s_barrier();
        __builtin_amdgcn_sched_barrier(0);
        if (t < 62) STAGE(cur, (t + 2) * 32);   // overwrite buf[cur] for t+2
        __builtin_amdgcn_s_setprio(1);
        #pragma unroll
        for (int s = 0; s < 2; s++) {
            #pragma unroll
            for (int mt = 0; mt < 2; mt++)
                #pragma unroll
                for (int nt2 = 0; nt2 < NTT; nt2++)
                    acc[mt][nt2] = __builtin_amdgcn_mfma_f32_32x32x16_f16(ahf[mt][s], bhf[nt2][s], acc[mt][nt2], 0, 0, 0);
            #pragma unroll
            for (int mt = 0; mt < 2; mt++)
                #pragma unroll
                for (int nt2 = 0; nt2 < NTT; nt2++)
                    acc[mt][nt2] = __builtin_amdgcn_mfma_f32_32x32x16_f16(alf[mt][s], bhf[nt2][s], acc[mt][nt2], 0, 0, 0);
            #pragma unroll
            for (int mt = 0; mt < 2; mt++)
                #pragma unroll
                for (int nt2 = 0; nt2 < NTT; nt2++)
                    acc[mt][nt2] = __builtin_amdgcn_mfma_f32_32x32x16_f16(ahf[mt][s], blf[nt2][s], acc[mt][nt2], 0, 0, 0);
        }
        __builtin_amdgcn_s_setprio(0);
        if (t < 63) {
            if (t < 62) {   // wait tile t+1 only; t+2's loads stay in flight
                if constexpr (NT == 4) asm volatile("s_waitcnt vmcnt(8)" ::: "memory");
                else                   asm volatile("s_waitcnt vmcnt(6)" ::: "memory");
            } else {        // pipeline drain before the final tile
                asm volatile("s_waitcnt vmcnt(0)" ::: "memory");
            }
            __builtin_amdgcn_s_barrier();
            __builtin_amdgcn_sched_barrier(0);
        }
    }

    // C/D layout (32x32): col = lane&31, row = (reg&3)+8*(reg>>2)+4*(lane>>5)
    int is_high = row0 < 2048;
    float bsum[2][16];
    #pragma unroll
    for (int mt = 0; mt < 2; mt++)
        #pragma unroll
        for (int r = 0; r < 16; r++) bsum[mt][r] = 0.f;

    #pragma unroll
    for (int nt2 = 0; nt2 < NTT; nt2++) {
        int gc = col0 + bbase + nt2 * 32 + l31;
        if (EPI == 0) {
            float cwl = wl[gc], cwh = wh[gc], cbh = bhr[gc], cbj = bj[gc];
            #pragma unroll
            for (int mt = 0; mt < 2; mt++) {
                #pragma unroll
                for (int r = 0; r < 16; r++) {
                    float m = acc[mt][nt2][r];
                    float t, bt;
                    if (is_high) { t = (m > 0.f) ? m * cwh : m * cwl; bt = fmaxf(m, 0.f) * cbh; }
                    else         { t = (m > 0.f) ? m * cwl : m * cwh; bt = fminf(m, 0.f) * cbh; }
                    bsum[mt][r] += bt + t * cbj;
                    int grow = row0 + wm * 64 + mt * 32 + (r & 3) + 8 * (r >> 2) + 4 * kh;
                    size_t o = (size_t)grow * 2048 + gc;
                    _Float16 h = (_Float16)t;
                    oAh[o] = h;
                    oAl[o] = (_Float16)(t - (float)h);
                }
            }
        } else {
            float clo = lo0[gc], chi = hi0[gc];
            #pragma unroll
            for (int mt = 0; mt < 2; mt++) {
                #pragma unroll
                for (int r = 0; r < 16; r++) {
                    float m = acc[mt][nt2][r];
                    float contrib;
                    if (is_high) contrib = (m < 0.f) ? m * clo : m * chi;
                    else         contrib = (m < 0.f) ? m * chi : m * clo;
                    bsum[mt][r] += contrib;
                }
            }
        }
    }
    #pragma unroll
    for (int mt = 0; mt < 2; mt++) {
        #pragma unroll
        for (int r = 0; r < 16; r++) {
            float v = bsum[mt][r];
            v += __shfl_xor(v, 1);
            v += __shfl_xor(v, 2);
            v += __shfl_xor(v, 4);
            v += __shfl_xor(v, 8);
            v += __shfl_xor(v, 16);   // reduces within each 32-lane half
            if (l31 == 0) {           // lanes 0 (kh=0) and 32 (kh=1)
                int grow = row0 + wm * 64 + mt * 32 + (r & 3) + 8 * (r >> 2) + 4 * kh;
                if (EPI == 0) atomicAdd(&bias[grow], v);
                else          atomicAdd(&box[grow], v);
            }
        }
    }
}

// Rec3 capture only (layer-4 consumers read materialized arrays).
__global__ void k_relu_rec(const float* __restrict__ box, const float* __restrict__ bias,
                           float* __restrict__ wl, float* __restrict__ wh,
                           float* __restrict__ bhr) {
    int i = blockIdx.x * blockDim.x + threadIdx.x;
    float h = box[i] + bias[i];
    float l = box[2048 + i] + bias[2048 + i];
    float vwl, vwh, vbh;
    relu_rec_calc(h, l, vwl, vwh, vbh);
    wl[i] = vwl; wh[i] = vwh; bhr[i] = vbh;
}

// Layer-4 fused: reduce prev partials (or W4 bcast) + relu-backsub transform
// in prologue, then split-K skinny GEMM. Rows 0..9 high, 10..19 low.
__global__ __launch_bounds__(256) void k_skinny2(
        const float* __restrict__ src, int bcast,
        const float* __restrict__ wl, const float* __restrict__ wh,
        const float* __restrict__ W, int N, float* __restrict__ Ppart) {
    __shared__ float sA[20 * 256];
    __shared__ float sRed[20 * 128];
    int ky = blockIdx.y, k0 = ky * 256;
    int tid = threadIdx.x;
    for (int idx = tid; idx < 20 * 256; idx += 256) {
        int r = idx >> 8, c = idx & 255;
        int gc = k0 + c;
        float m;
        if (bcast) m = src[(size_t)(r % 10) * 2048 + gc];
        else {
            m = 0.f;
            #pragma unroll
            for (int p = 0; p < 8; p++)
                m += src[(size_t)p * 40960 + (size_t)r * 2048 + gc];
        }
        float t = (r < 10) ? ((m > 0.f) ? m * wh[gc] : m * wl[gc])
                           : ((m > 0.f) ? m * wl[gc] : m * wh[gc]);
        sA[idx] = t;
    }
    __syncthreads();
    int c = blockIdx.x * 128 + (tid & 127);
    int kh = tid >> 7;
    float acc[20];
    #pragma unroll
    for (int r = 0; r < 20; r++) acc[r] = 0.f;
    if (c < N) {
        const float* Wp = W + (size_t)(k0 + kh * 128) * N + c;
        for (int kk = 0; kk < 128; kk++) {
            float w = Wp[(size_t)kk * N];
            #pragma unroll
            for (int r = 0; r < 20; r++) acc[r] += sA[r * 256 + kh * 128 + kk] * w;
        }
    }
    if (kh == 1 && c < N) {
        #pragma unroll
        for (int r = 0; r < 20; r++) sRed[r * 128 + (tid & 127)] = acc[r];
    }
    __syncthreads();
    if (kh == 0 && c < N) {
        #pragma unroll
        for (int r = 0; r < 20; r++)
            Ppart[(size_t)ky * 40960 + (size_t)r * 2048 + c] =
                acc[r] + sRed[r * 128 + (tid & 127)];
    }
}

// All four layer-4 bias dots + the forward matvec (out[0..9]) in one kernel.
__global__ void k_bias20(const float* __restrict__ W4,
                         const float* __restrict__ PPa, const float* __restrict__ PPb,
                         const float* __restrict__ PPc,
                         const float* __restrict__ WLr, const float* __restrict__ WHr,
                         const float* __restrict__ BHr,
                         const float* __restrict__ b0, const float* __restrict__ b1,
                         const float* __restrict__ b2, const float* __restrict__ b3,
                         const float* __restrict__ b4,
                         const float* __restrict__ x3,
                         float* __restrict__ bias20, float* __restrict__ out) {
    int row = blockIdx.x;
    int is_high = row < 10;
    int srow = row % 10;
    float acc = 0.f, accx = 0.f;
    for (int c = threadIdx.x; c < 2048; c += 256) {
        {   // rec3 on W4 (+ forward matvec with relu'd x3)
            float m = W4[(size_t)srow * 2048 + c];
            float wlv = WLr[3 * 2048 + c], whv = WHr[3 * 2048 + c], bhv = BHr[3 * 2048 + c];
            float t  = is_high ? ((m > 0.f) ? m * whv : m * wlv) : ((m > 0.f) ? m * wlv : m * whv);
            float bt = is_high ? fmaxf(m, 0.f) * bhv : fminf(m, 0.f) * bhv;
            acc += bt + t * b3[c];
            accx += m * fmaxf(x3[c], 0.f);
        }
        {   // rec2 on sum PPa
            float m = 0.f;
            #pragma unroll
            for (int p = 0; p < 8; p++) m += PPa[(size_t)p * 40960 + (size_t)row * 2048 + c];
            float wlv = WLr[2 * 2048 + c], whv = WHr[2 * 2048 + c], bhv = BHr[2 * 2048 + c];
            float t  = is_high ? ((m > 0.f) ? m * whv : m * wlv) : ((m > 0.f) ? m * wlv : m * whv);
            float bt = is_high ? fmaxf(m, 0.f) * bhv : fminf(m, 0.f) * bhv;
            acc += bt + t * b2[c];
        }
        {   // rec1 on sum PPb
            float m = 0.f;
            #pragma unroll
            for (int p = 0; p < 8; p++) m += PPb[(size_t)p * 40960 + (size_t)row * 2048 + c];
            float wlv = WLr[1 * 2048 + c], whv = WHr[1 * 2048 + c], bhv = BHr[1 * 2048 + c];
            float t  = is_high ? ((m > 0.f) ? m * whv : m * wlv) : ((m > 0.f) ? m * wlv : m * whv);
            float bt = is_high ? fmaxf(m, 0.f) * bhv : fminf(m, 0.f) * bhv;
            acc += bt + t * b1[c];
        }
        {   // rec0 on sum PPc
            float m = 0.f;
            #pragma unroll
            for (int p = 0; p < 8; p++) m += PPc[(size_t)p * 40960 + (size_t)row * 2048 + c];
            float wlv = WLr[c], whv = WHr[c], bhv = BHr[c];
            float t  = is_high ? ((m > 0.f) ? m * whv : m * wlv) : ((m > 0.f) ? m * wlv : m * whv);
            float bt = is_high ? fmaxf(m, 0.f) * bhv : fminf(m, 0.f) * bhv;
            acc += bt + t * b0[c];
        }
    }
    float2 rr = blockReduce256x2(acc, accx);
    if (threadIdx.x == 0) {
        bias20[row] = b4[srow] + rr.x;
        if (is_high) out[row] = b4[row] + rr.y;
    }
}

// Final layer-4 interval matvec from 8 split-K parts.
__global__ void k_fbox20(const float* __restrict__ Ppart,
                         const float* __restrict__ bias20,
                         const float* __restrict__ lo0, const float* __restrict__ hi0,
                         float* __restrict__ out) {
    int row = blockIdx.x;
    int is_high = row < 10;
    float acc = 0.f;
    for (int c = threadIdx.x; c < 784; c += 256) {
        float m = 0.f;
        #pragma unroll
        for (int p = 0; p < 8; p++)
            m += Ppart[(size_t)p * 40960 + (size_t)row * 2048 + c];
        if (is_high) acc += (m < 0.f) ? m * lo0[c] : m * hi0[c];
        else         acc += (m < 0.f) ? m * hi0[c] : m * lo0[c];
    }
    acc = blockReduce256(acc);
    if (threadIdx.x == 0) {
        float v = acc + bias20[row];
        out[is_high ? (20 + row) : row] = v;
    }
}

extern "C" void kernel_launch(void* const* d_in, const int* in_sizes, int n_in,
                              void* d_out, int out_size, void* d_ws, size_t ws_size,
                              hipStream_t stream) {
    const float* x_in  = (const float*)d_in[0];
    const float* lo_in = (const float*)d_in[1];
    const float* hi_in = (const float*)d_in[2];
    const float* W[5];
    const float* bv[5];
    for (int i = 0; i < 5; i++) {
        W[i]  = (const float*)d_in[3 + 2 * i];
        bv[i] = (const float*)d_in[4 + 2 * i];
    }
    float* ws = (float*)d_ws;
    float* out = (float*)d_out;

    float* X[2]    = {ws + OFF_X0, ws + OFF_X1};
    float* lo0     = ws + OFF_L0;
    float* hi0     = ws + OFF_H0;
    float* BOX[2]  = {ws + OFF_BOXA, ws + OFF_BOXB};
    float* BIAS[2] = {ws + OFF_BIASA, ws + OFF_BIASB};
    float* b20     = ws + OFF_B20;
    float* PPa     = ws + OFF_PPA;
    float* PPb     = ws + OFF_PPB;
    float* PPc     = ws + OFF_PPC;
    float* PPd     = ws + OFF_PPD;
    _Float16* WT_H[3] = {(_Float16*)(ws + OFF_W0TH), (_Float16*)(ws + OFF_W1TH),
                         (_Float16*)(ws + OFF_W2TH)};
    _Float16* WT_L[3] = {(_Float16*)(ws + OFF_W0TL), (_Float16*)(ws + OFF_W1TL),
                         (_Float16*)(ws + OFF_W2TL)};
    _Float16* AH[2] = {(_Float16*)(ws + OFF_AH0), (_Float16*)(ws + OFF_AH1)};
    _Float16* AL[2] = {(_Float16*)(ws + OFF_AL0), (_Float16*)(ws + OFF_AL1)};
    float* WLr = ws + OFF_WL;
    float* WHr = ws + OFF_WH;
    float* BHr = ws + OFF_BHR;

    k_norm<<<4, 256, 0, stream>>>(x_in, lo_in, hi_in, ws);
    // hoisted transposes (input-only dependencies)
    k_transpose_split<<<dim3(28, 64), 256, 0, stream>>>(W[0], 784, WT_H[0], WT_L[0]);
    k_transpose_split<<<dim3(64, 64), 256, 0, stream>>>(W[1], 2048, WT_H[1], WT_L[1]);
    k_transpose_split<<<dim3(64, 64), 256, 0, stream>>>(W[2], 2048, WT_H[2], WT_L[2]);

    // ---- layer 0 ----
    k_fboxes0<<<4096, 256, 0, stream>>>(W[0], bv[0], X[0], lo0, hi0, BOX[0], X[1]);

    // ---- layers 1..3 ----
    int xcur = 1, bprev = 0;   // BOX[bprev] = prev layer bounds; bias ping-pong
    const float* biasPrev = nullptr;
    for (int i = 1; i <= 3; i++) {
        int xnxt = xcur ^ 1;
        int bcur = bprev ^ 1;
        float* biasCur = BIAS[(i - 1) & 1];
        k_relu_split<<<4096, 256, 0, stream>>>(
            W[i], X[xcur], BOX[bprev], biasPrev,
            WLr + (i - 1) * 2048, WHr + (i - 1) * 2048, BHr + (i - 1) * 2048,
            bv[i - 1], bv[i], biasCur, BOX[bcur], X[xnxt], AH[0], AL[0]);
        int p = 0;
        for (int j = i - 1; j >= 1; j--) {
            k_gemm<4, 0><<<dim3(16, 32), 256, 0, stream>>>(
                AH[p], AL[p], WT_H[j], WT_L[j],
                WLr + (j - 1) * 2048, WHr + (j - 1) * 2048,
                BHr + (j - 1) * 2048, bv[j - 1], biasCur,
                AH[p ^ 1], AL[p ^ 1], nullptr, nullptr, nullptr);
            p ^= 1;
        }
        k_gemm<2, 1><<<dim3(14, 32), 256, 0, stream>>>(
            AH[p], AL[p], WT_H[0], WT_L[0],
            nullptr, nullptr, nullptr, nullptr, nullptr,
            nullptr, nullptr, lo0, hi0, BOX[bcur]);
        biasPrev = biasCur;
        bprev = bcur;
        xcur = xnxt;
    }
    // rec3 for the layer-4 path (BIAS[(3-1)&1] = BIAS[0])
    k_relu_rec<<<8, 256, 0, stream>>>(BOX[bprev], BIAS[0],
                                      WLr + 3 * 2048, WHr + 3 * 2048, BHr + 3 * 2048);

    // ---- layer 4: 20-row chains (split-K partial path) ----
    k_skinny2<<<dim3(16, 8), 256, 0, stream>>>(W[4], 1,
        WLr + 3 * 2048, WHr + 3 * 2048, W[3], 2048, PPa);
    k_skinny2<<<dim3(16, 8), 256, 0, stream>>>(PPa, 0,
        WLr + 2 * 2048, WHr + 2 * 2048, W[2], 2048, PPb);
    k_skinny2<<<dim3(16, 8), 256, 0, stream>>>(PPb, 0,
        WLr + 1 * 2048, WHr + 1 * 2048, W[1], 2048, PPc);
    k_skinny2<<<dim3(7, 8), 256, 0, stream>>>(PPc, 0,
        WLr, WHr, W[0], 784, PPd);
    k_bias20<<<20, 256, 0, stream>>>(W[4], PPa, PPb, PPc,
        WLr, WHr, BHr, bv[0], bv[1], bv[2], bv[3], bv[4], X[xcur], b20, out);
    k_fbox20<<<20, 256, 0, stream>>>(PPd, b20, lo0, hi0, out);
}

// Round 13
// 839.457 us; speedup vs baseline: 1.0820x; 1.0663x over previous
//
#include <hip/hip_runtime.h>
#include <hip/hip_bf16.h>

// DeepPoly MLP verifier (784->2048x4->10).
// Round 18 RESUBMIT (two infra failures; this source == r15, measured
// 829us in round 8 — best configuration).
// Ledger: depth-2 counted-vmcnt pipeline (r8/r9) + conflict-free LDS
// swizzle key (row>>1)&3 (r9, conflicts=0) + T5 setprio (r11, +6us/disp)
// + XCD-aware block swizzle (r15, FETCH 139->83MB, +15us total).
// Closed lines: intra-wave read/MFMA overlap (r12/13/14/16 all regressed;
// convoy structure can't express it), 32x32 shape (r17, bank conflicts).

#define MEAN_C 0.1307f
#define STD_C  0.3081f

// ---- workspace offsets (floats), total ~108.2 MB ----
#define OFF_X0     0u
#define OFF_X1     2048u
#define OFF_L0     4096u       // 896 used (zero-padded)
#define OFF_H0     5120u
#define OFF_WL     6144u       // 4*2048 (rec j at +j*2048)
#define OFF_WH     14336u
#define OFF_BHR    22528u
#define OFF_BOXA   30720u      // 4096
#define OFF_BOXB   34816u
#define OFF_BIASA  38912u      // 4096
#define OFF_BIASB  43008u
#define OFF_B20    47104u      // 32
#define OFF_W0TH   47136u      // f16 [896][2048]  = 917504 float-slots
#define OFF_W0TL   964640u
#define OFF_W1TH   1882144u    // f16 [2048][2048] = 2097152 float-slots
#define OFF_W1TL   3979296u
#define OFF_W2TH   6076448u
#define OFF_W2TL   8173600u
#define OFF_AH0    10270752u   // f16 [4096][2048] = 4194304 float-slots
#define OFF_AL0    14465056u
#define OFF_AH1    18659360u
#define OFF_AL1    22853664u
// PP split-K partials alias into AH1 (free during layer 4): 4 x 327680 floats
#define OFF_PPA    18659360u
#define OFF_PPB    18987040u
#define OFF_PPC    19314720u
#define OFF_PPD    19642400u
// end 27047968 floats

typedef _Float16 half8 __attribute__((ext_vector_type(8)));
typedef float floatx4 __attribute__((ext_vector_type(4)));

__device__ __forceinline__ void gl2lds16(const void* g, void* l) {
    __builtin_amdgcn_global_load_lds(
        (const __attribute__((address_space(1))) unsigned int*)g,
        (__attribute__((address_space(3))) unsigned int*)l, 16, 0, 0);
}

__device__ __forceinline__ float blockReduce256(float v) {
    #pragma unroll
    for (int o = 32; o > 0; o >>= 1) v += __shfl_down(v, o, 64);
    __shared__ float sred[4];
    int w = threadIdx.x >> 6;
    if ((threadIdx.x & 63) == 0) sred[w] = v;
    __syncthreads();
    float r = 0.f;
    if (threadIdx.x == 0) r = sred[0] + sred[1] + sred[2] + sred[3];
    return r;
}

__device__ __forceinline__ float2 blockReduce256x2(float a, float b) {
    #pragma unroll
    for (int o = 32; o > 0; o >>= 1) {
        a += __shfl_down(a, o, 64);
        b += __shfl_down(b, o, 64);
    }
    __shared__ float sa[4], sb[4];
    int w = threadIdx.x >> 6;
    if ((threadIdx.x & 63) == 0) { sa[w] = a; sb[w] = b; }
    __syncthreads();
    float2 r = {0.f, 0.f};
    if (threadIdx.x == 0) {
        r.x = sa[0] + sa[1] + sa[2] + sa[3];
        r.y = sb[0] + sb[1] + sb[2] + sb[3];
    }
    return r;
}

// DeepPoly relu relaxation from bounds (h,l).
__device__ __forceinline__ void relu_rec_calc(float h, float l,
                                              float& vwl, float& vwh, float& vbh) {
    if (h <= 0.f)      { vwl = 0.f; vwh = 0.f; vbh = 0.f; }
    else if (l >= 0.f) { vwl = 1.f; vwh = 1.f; vbh = 0.f; }
    else {
        float d = h - l;
        vwh = h / d;
        vbh = -(l * h) / d;
        vwl = (l * l > h * h) ? 0.f : 1.f;
    }
}

__global__ void k_norm(const float* __restrict__ x, const float* __restrict__ lo,
                       const float* __restrict__ hi, float* __restrict__ ws) {
    int i = blockIdx.x * blockDim.x + threadIdx.x;
    if (i < 784) {
        ws[OFF_X0 + i] = (x[i]  - MEAN_C) / STD_C;
        ws[OFF_L0 + i] = (lo[i] - MEAN_C) / STD_C;
        ws[OFF_H0 + i] = (hi[i] - MEAN_C) / STD_C;
    } else if (i < 896) {
        ws[OFF_L0 + i] = 0.f;
        ws[OFF_H0 + i] = 0.f;
    }
}

// Layer-0 interval matvec + forward matvec fused.
__global__ void k_fboxes0(const float* __restrict__ W0, const float* __restrict__ b0,
                          const float* __restrict__ x0,
                          const float* __restrict__ lo0, const float* __restrict__ hi0,
                          float* __restrict__ box, float* __restrict__ xout) {
    int r = blockIdx.x;
    int srow = r & 2047;
    int is_high = r < 2048;
    const float* Wr = W0 + (size_t)srow * 784;
    float acc = 0.f, accx = 0.f;
    for (int c = threadIdx.x; c < 784; c += 256) {
        float m = Wr[c];
        if (is_high) acc += (m < 0.f) ? m * lo0[c] : m * hi0[c];
        else         acc += (m < 0.f) ? m * hi0[c] : m * lo0[c];
        accx += m * x0[c];
    }
    float2 rr = blockReduce256x2(acc, accx);
    if (threadIdx.x == 0) {
        box[r] = rr.x + b0[srow];
        if (is_high) xout[r] = rr.y + b0[r];
    }
}

// First backsub step of layer i, with INLINE relu-record computation from
// (boxPrev, biasPrev): T_{i-1}(W_i) stacked (4096 rows) -> f16 hi/lo A;
// bias = bv_i + (bhr dot + T@b_{i-1}); block 0 materializes rec arrays;
// thread 0 zeroes boxOut[row]; rows<2048 also compute y = W_i@relu(x)+bv_i.
__global__ __launch_bounds__(256) void k_relu_split(
        const float* __restrict__ Wi, const float* __restrict__ xin,
        const float* __restrict__ boxPrev, const float* __restrict__ biasPrev,
        float* __restrict__ recWL, float* __restrict__ recWH, float* __restrict__ recBH,
        const float* __restrict__ bj, const float* __restrict__ bvi,
        float* __restrict__ bias, float* __restrict__ boxOut,
        float* __restrict__ xout,
        _Float16* __restrict__ Ahi, _Float16* __restrict__ Alo) {
    int row = blockIdx.x;
    int is_high = row < 2048;
    int srow = row & 2047;
    const float* src = Wi + (size_t)srow * 2048;
    int c0 = threadIdx.x * 8;
    float mv[8], bxh[8], bxl[8], abj[8], ax[8];
    *(float4*)&mv[0]  = *(const float4*)(src + c0);
    *(float4*)&mv[4]  = *(const float4*)(src + c0 + 4);
    *(float4*)&bxh[0] = *(const float4*)(boxPrev + c0);
    *(float4*)&bxh[4] = *(const float4*)(boxPrev + c0 + 4);
    *(float4*)&bxl[0] = *(const float4*)(boxPrev + 2048 + c0);
    *(float4*)&bxl[4] = *(const float4*)(boxPrev + 2048 + c0 + 4);
    *(float4*)&abj[0] = *(const float4*)(bj + c0);
    *(float4*)&abj[4] = *(const float4*)(bj + c0 + 4);
    *(float4*)&ax[0]  = *(const float4*)(xin + c0);
    *(float4*)&ax[4]  = *(const float4*)(xin + c0 + 4);
    if (biasPrev) {
        float ph[8], pl[8];
        *(float4*)&ph[0] = *(const float4*)(biasPrev + c0);
        *(float4*)&ph[4] = *(const float4*)(biasPrev + c0 + 4);
        *(float4*)&pl[0] = *(const float4*)(biasPrev + 2048 + c0);
        *(float4*)&pl[4] = *(const float4*)(biasPrev + 2048 + c0 + 4);
        #pragma unroll
        for (int e = 0; e < 8; e++) { bxh[e] += ph[e]; bxl[e] += pl[e]; }
    }
    float acc = 0.f, accx = 0.f;
    float rl[8], rh[8], rb[8];
    half8 hi, lo;
    #pragma unroll
    for (int e = 0; e < 8; e++) {
        relu_rec_calc(bxh[e], bxl[e], rl[e], rh[e], rb[e]);
        float m = mv[e];
        float t, bt;
        if (is_high) { t = (m > 0.f) ? m * rh[e] : m * rl[e]; bt = fmaxf(m, 0.f) * rb[e]; }
        else         { t = (m > 0.f) ? m * rl[e] : m * rh[e]; bt = fminf(m, 0.f) * rb[e]; }
        acc += bt + t * abj[e];
        accx += m * fmaxf(ax[e], 0.f);
        _Float16 h = (_Float16)t;
        hi[e] = h;
        lo[e] = (_Float16)(t - (float)h);
    }
    *(half8*)(Ahi + (size_t)row * 2048 + c0) = hi;
    *(half8*)(Alo + (size_t)row * 2048 + c0) = lo;
    if (row == 0) {   // materialize rec arrays for later consumers
        *(float4*)(recWL + c0) = *(float4*)&rl[0];
        *(float4*)(recWL + c0 + 4) = *(float4*)&rl[4];
        *(float4*)(recWH + c0) = *(float4*)&rh[0];
        *(float4*)(recWH + c0 + 4) = *(float4*)&rh[4];
        *(float4*)(recBH + c0) = *(float4*)&rb[0];
        *(float4*)(recBH + c0 + 4) = *(float4*)&rb[4];
    }
    float2 rr = blockReduce256x2(acc, accx);
    if (threadIdx.x == 0) {
        bias[row] = bvi[srow] + rr.x;
        boxOut[row] = 0.f;
        if (is_high) xout[row] = rr.y + bvi[row];
    }
}

// Transpose + f16 hi/lo split: Wt[n][k] = W[k][n]; pad n in [NC,NP) with 0.
__global__ void k_transpose_split(const float* __restrict__ W, int NC,
                                  _Float16* __restrict__ Thi,
                                  _Float16* __restrict__ Tlo) {
    __shared__ float s[32][33];
    int c = threadIdx.x & 31;
    int r = threadIdx.x >> 5;
    #pragma unroll
    for (int rr = 0; rr < 4; rr++) {
        int k = blockIdx.y * 32 + r + rr * 8;
        int n = blockIdx.x * 32 + c;
        float v = (n < NC) ? W[(size_t)k * NC + n] : 0.f;
        s[c][r + rr * 8] = v;
    }
    __syncthreads();
    #pragma unroll
    for (int rr = 0; rr < 4; rr++) {
        int nl = r + rr * 8;
        float v = s[nl][c];
        _Float16 h = (_Float16)v;
        size_t o = (size_t)(blockIdx.x * 32 + nl) * 2048 + blockIdx.y * 32 + c;
        Thi[o] = h;
        Tlo[o] = (_Float16)(v - (float)h);
    }
}

// C[4096,NP] = (Ah+Al) @ (Bh+Bl)^T, 3 f16 products. BM=128, BN=NT*32,
// BK=32; 256 threads. Depth-2 counted-vmcnt pipeline (r9) + T5 setprio
// (r11) + XCD-aware block swizzle (r15): consecutive-XCD blocks get
// contiguous tile ranges so shared A/B panels stay in the XCD's L2.
// EPI 0: relu-backsub epilogue (emit next Ah/Al + bias atomics).
// EPI 1: interval-matvec epilogue (atomics into pre-zeroed BOX).
template<int NT, int EPI>
__global__ __launch_bounds__(256, 2) void k_gemm(
        const _Float16* __restrict__ Ah, const _Float16* __restrict__ Al,
        const _Float16* __restrict__ Bh, const _Float16* __restrict__ Bl,
        const float* __restrict__ wl, const float* __restrict__ wh,
        const float* __restrict__ bhr, const float* __restrict__ bj,
        float* __restrict__ bias,
        _Float16* __restrict__ oAh, _Float16* __restrict__ oAl,
        const float* __restrict__ lo0, const float* __restrict__ hi0,
        float* __restrict__ box) {
    __shared__ _Float16 sAh[2][128 * 32], sAl[2][128 * 32];
    __shared__ _Float16 sBh[2][NT * 32 * 32], sBl[2][NT * 32 * 32];
    int tid = threadIdx.x;

    // XCD-aware swizzle: nwg (512 or 448) is divisible by 8 -> bijective.
    int gx = gridDim.x;
    int bid = blockIdx.y * gx + blockIdx.x;
    int cpx = (gx * gridDim.y) >> 3;
    int l   = (bid & 7) * cpx + (bid >> 3);
    int bx  = l % gx;
    int by  = l / gx;
    int row0 = by * 128, col0 = bx * (NT * 32);

    int cr = tid >> 2;
    int q  = (tid & 3) ^ ((cr >> 1) & 3);   // bank swizzle at fetch (keyed on row>>1)
    const _Float16* gAh0 = Ah + (size_t)(row0 + cr) * 2048 + q * 8;
    const _Float16* gAh1 = gAh0 + (size_t)64 * 2048;
    const _Float16* gAl0 = Al + (size_t)(row0 + cr) * 2048 + q * 8;
    const _Float16* gAl1 = gAl0 + (size_t)64 * 2048;
    const _Float16* gBh0 = Bh + (size_t)(col0 + cr) * 2048 + q * 8;
    const _Float16* gBl0 = Bl + (size_t)(col0 + cr) * 2048 + q * 8;
    const _Float16* gBh1 = gBh0 + (size_t)64 * 2048;   // NT==4 only
    const _Float16* gBl1 = gBl0 + (size_t)64 * 2048;
    int loff = tid * 8;

    int lane = tid & 63, wv = tid >> 6;
    int wm = wv & 1, wn = wv >> 1;
    int l15 = lane & 15, lq = lane >> 4;
    int soff = (lq ^ ((l15 >> 1) & 3)) * 8;  // matches write-side swizzle
    int arow = wm * 64 + l15;
    int brow = wn * (NT * 16) + l15;

    floatx4 acc[4][NT];
    floatx4 z = {0.f, 0.f, 0.f, 0.f};
    #pragma unroll
    for (int i = 0; i < 4; i++)
        #pragma unroll
        for (int j = 0; j < NT; j++) acc[i][j] = z;

    // per-wave loads per K-tile: NT==4 -> 8, NT==2 -> 6
    auto STAGE = [&](int b, int k0) {
        gl2lds16(gAh0 + k0, &sAh[b][loff]);
        gl2lds16(gAh1 + k0, &sAh[b][loff + 2048]);
        gl2lds16(gAl0 + k0, &sAl[b][loff]);
        gl2lds16(gAl1 + k0, &sAl[b][loff + 2048]);
        gl2lds16(gBh0 + k0, &sBh[b][loff]);
        gl2lds16(gBl0 + k0, &sBl[b][loff]);
        if (NT == 4) {
            gl2lds16(gBh1 + k0, &sBh[b][loff + 2048]);
            gl2lds16(gBl1 + k0, &sBl[b][loff + 2048]);
        }
    };

    STAGE(0, 0);
    STAGE(1, 32);
    if constexpr (NT == 4) asm volatile("s_waitcnt vmcnt(8)" ::: "memory");
    else                   asm volatile("s_waitcnt vmcnt(6)" ::: "memory");
    __builtin_amdgcn_s_barrier();
    __builtin_amdgcn_sched_barrier(0);

    for (int t = 0; t < 64; ++t) {
        int cur = t & 1;
        half8 bh[NT], bl[NT], ah4[4], al4[4];
        #pragma unroll
        for (int nt = 0; nt < NT; nt++) {
            bh[nt] = *(const half8*)&sBh[cur][(brow + nt * 16) * 32 + soff];
            bl[nt] = *(const half8*)&sBl[cur][(brow + nt * 16) * 32 + soff];
        }
        #pragma unroll
        for (int mt = 0; mt < 4; mt++) {
            ah4[mt] = *(const half8*)&sAh[cur][(arow + mt * 16) * 32 + soff];
            al4[mt] = *(const half8*)&sAl[cur][(arow + mt * 16) * 32 + soff];
        }
        // all reads of buf[cur] retired before anyone overwrites it
        asm volatile("s_waitcnt lgkmcnt(0)" ::: "memory");
        __builtin_amdgcn_sched_barrier(0);
        __builtin_amdgcn_s_barrier();
        __builtin_amdgcn_sched_barrier(0);
        if (t < 62) STAGE(cur, (t + 2) * 32);   // overwrite buf[cur] for t+2
        __builtin_amdgcn_s_setprio(1);
        #pragma unroll
        for (int mt = 0; mt < 4; mt++) {
            #pragma unroll
            for (int nt = 0; nt < NT; nt++) {
                acc[mt][nt] = __builtin_amdgcn_mfma_f32_16x16x32_f16(ah4[mt], bh[nt], acc[mt][nt], 0, 0, 0);
                acc[mt][nt] = __builtin_amdgcn_mfma_f32_16x16x32_f16(al4[mt], bh[nt], acc[mt][nt], 0, 0, 0);
                acc[mt][nt] = __builtin_amdgcn_mfma_f32_16x16x32_f16(ah4[mt], bl[nt], acc[mt][nt], 0, 0, 0);
            }
        }
        __builtin_amdgcn_s_setprio(0);
        if (t < 63) {
            if (t < 62) {   // wait tile t+1 only; t+2's loads stay in flight
                if constexpr (NT == 4) asm volatile("s_waitcnt vmcnt(8)" ::: "memory");
                else                   asm volatile("s_waitcnt vmcnt(6)" ::: "memory");
            } else {        // pipeline drain before the final tile
                asm volatile("s_waitcnt vmcnt(0)" ::: "memory");
            }
            __builtin_amdgcn_s_barrier();
            __builtin_amdgcn_sched_barrier(0);
        }
    }

    // C/D layout: col = lane&15, row = (lane>>4)*4 + reg
    int is_high = row0 < 2048;
    float bsum[4][4];
    #pragma unroll
    for (int mt = 0; mt < 4; mt++)
        #pragma unroll
        for (int r = 0; r < 4; r++) bsum[mt][r] = 0.f;

    #pragma unroll
    for (int nt = 0; nt < NT; nt++) {
        int gc = col0 + wn * (NT * 16) + nt * 16 + l15;
        if (EPI == 0) {
            float cwl = wl[gc], cwh = wh[gc], cbh = bhr[gc], cbj = bj[gc];
            #pragma unroll
            for (int mt = 0; mt < 4; mt++) {
                #pragma unroll
                for (int r = 0; r < 4; r++) {
                    float m = acc[mt][nt][r];
                    float t, bt;
                    if (is_high) { t = (m > 0.f) ? m * cwh : m * cwl; bt = fmaxf(m, 0.f) * cbh; }
                    else         { t = (m > 0.f) ? m * cwl : m * cwh; bt = fminf(m, 0.f) * cbh; }
                    bsum[mt][r] += bt + t * cbj;
                    int grow = row0 + wm * 64 + mt * 16 + lq * 4 + r;
                    size_t o = (size_t)grow * 2048 + gc;
                    _Float16 h = (_Float16)t;
                    oAh[o] = h;
                    oAl[o] = (_Float16)(t - (float)h);
                }
            }
        } else {
            float clo = lo0[gc], chi = hi0[gc];
            #pragma unroll
            for (int mt = 0; mt < 4; mt++) {
                #pragma unroll
                for (int r = 0; r < 4; r++) {
                    float m = acc[mt][nt][r];
                    float contrib;
                    if (is_high) contrib = (m < 0.f) ? m * clo : m * chi;
                    else         contrib = (m < 0.f) ? m * chi : m * clo;
                    bsum[mt][r] += contrib;
                }
            }
        }
    }
    #pragma unroll
    for (int mt = 0; mt < 4; mt++) {
        #pragma unroll
        for (int r = 0; r < 4; r++) {
            float v = bsum[mt][r];
            v += __shfl_xor(v, 1);
            v += __shfl_xor(v, 2);
            v += __shfl_xor(v, 4);
            v += __shfl_xor(v, 8);
            if (l15 == 0) {
                int grow = row0 + wm * 64 + mt * 16 + lq * 4 + r;
                if (EPI == 0) atomicAdd(&bias[grow], v);
                else          atomicAdd(&box[grow], v);
            }
        }
    }
}

// Rec3 capture only (layer-4 consumers read materialized arrays).
__global__ void k_relu_rec(const float* __restrict__ box, const float* __restrict__ bias,
                           float* __restrict__ wl, float* __restrict__ wh,
                           float* __restrict__ bhr) {
    int i = blockIdx.x * blockDim.x + threadIdx.x;
    float h = box[i] + bias[i];
    float l = box[2048 + i] + bias[2048 + i];
    float vwl, vwh, vbh;
    relu_rec_calc(h, l, vwl, vwh, vbh);
    wl[i] = vwl; wh[i] = vwh; bhr[i] = vbh;
}

// Layer-4 fused: reduce prev partials (or W4 bcast) + relu-backsub transform
// in prologue, then split-K skinny GEMM. Rows 0..9 high, 10..19 low.
__global__ __launch_bounds__(256) void k_skinny2(
        const float* __restrict__ src, int bcast,
        const float* __restrict__ wl, const float* __restrict__ wh,
        const float* __restrict__ W, int N, float* __restrict__ Ppart) {
    __shared__ float sA[20 * 256];
    __shared__ float sRed[20 * 128];
    int ky = blockIdx.y, k0 = ky * 256;
    int tid = threadIdx.x;
    for (int idx = tid; idx < 20 * 256; idx += 256) {
        int r = idx >> 8, c = idx & 255;
        int gc = k0 + c;
        float m;
        if (bcast) m = src[(size_t)(r % 10) * 2048 + gc];
        else {
            m = 0.f;
            #pragma unroll
            for (int p = 0; p < 8; p++)
                m += src[(size_t)p * 40960 + (size_t)r * 2048 + gc];
        }
        float t = (r < 10) ? ((m > 0.f) ? m * wh[gc] : m * wl[gc])
                           : ((m > 0.f) ? m * wl[gc] : m * wh[gc]);
        sA[idx] = t;
    }
    __syncthreads();
    int c = blockIdx.x * 128 + (tid & 127);
    int kh = tid >> 7;
    float acc[20];
    #pragma unroll
    for (int r = 0; r < 20; r++) acc[r] = 0.f;
    if (c < N) {
        const float* Wp = W + (size_t)(k0 + kh * 128) * N + c;
        for (int kk = 0; kk < 128; kk++) {
            float w = Wp[(size_t)kk * N];
            #pragma unroll
            for (int r = 0; r < 20; r++) acc[r] += sA[r * 256 + kh * 128 + kk] * w;
        }
    }
    if (kh == 1 && c < N) {
        #pragma unroll
        for (int r = 0; r < 20; r++) sRed[r * 128 + (tid & 127)] = acc[r];
    }
    __syncthreads();
    if (kh == 0 && c < N) {
        #pragma unroll
        for (int r = 0; r < 20; r++)
            Ppart[(size_t)ky * 40960 + (size_t)r * 2048 + c] =
                acc[r] + sRed[r * 128 + (tid & 127)];
    }
}

// All four layer-4 bias dots + the forward matvec (out[0..9]) in one kernel.
__global__ void k_bias20(const float* __restrict__ W4,
                         const float* __restrict__ PPa, const float* __restrict__ PPb,
                         const float* __restrict__ PPc,
                         const float* __restrict__ WLr, const float* __restrict__ WHr,
                         const float* __restrict__ BHr,
                         const float* __restrict__ b0, const float* __restrict__ b1,
                         const float* __restrict__ b2, const float* __restrict__ b3,
                         const float* __restrict__ b4,
                         const float* __restrict__ x3,
                         float* __restrict__ bias20, float* __restrict__ out) {
    int row = blockIdx.x;
    int is_high = row < 10;
    int srow = row % 10;
    float acc = 0.f, accx = 0.f;
    for (int c = threadIdx.x; c < 2048; c += 256) {
        {   // rec3 on W4 (+ forward matvec with relu'd x3)
            float m = W4[(size_t)srow * 2048 + c];
            float wlv = WLr[3 * 2048 + c], whv = WHr[3 * 2048 + c], bhv = BHr[3 * 2048 + c];
            float t  = is_high ? ((m > 0.f) ? m * whv : m * wlv) : ((m > 0.f) ? m * wlv : m * whv);
            float bt = is_high ? fmaxf(m, 0.f) * bhv : fminf(m, 0.f) * bhv;
            acc += bt + t * b3[c];
            accx += m * fmaxf(x3[c], 0.f);
        }
        {   // rec2 on sum PPa
            float m = 0.f;
            #pragma unroll
            for (int p = 0; p < 8; p++) m += PPa[(size_t)p * 40960 + (size_t)row * 2048 + c];
            float wlv = WLr[2 * 2048 + c], whv = WHr[2 * 2048 + c], bhv = BHr[2 * 2048 + c];
            float t  = is_high ? ((m > 0.f) ? m * whv : m * wlv) : ((m > 0.f) ? m * wlv : m * whv);
            float bt = is_high ? fmaxf(m, 0.f) * bhv : fminf(m, 0.f) * bhv;
            acc += bt + t * b2[c];
        }
        {   // rec1 on sum PPb
            float m = 0.f;
            #pragma unroll
            for (int p = 0; p < 8; p++) m += PPb[(size_t)p * 40960 + (size_t)row * 2048 + c];
            float wlv = WLr[1 * 2048 + c], whv = WHr[1 * 2048 + c], bhv = BHr[1 * 2048 + c];
            float t  = is_high ? ((m > 0.f) ? m * whv : m * wlv) : ((m > 0.f) ? m * wlv : m * whv);
            float bt = is_high ? fmaxf(m, 0.f) * bhv : fminf(m, 0.f) * bhv;
            acc += bt + t * b1[c];
        }
        {   // rec0 on sum PPc
            float m = 0.f;
            #pragma unroll
            for (int p = 0; p < 8; p++) m += PPc[(size_t)p * 40960 + (size_t)row * 2048 + c];
            float wlv = WLr[c], whv = WHr[c], bhv = BHr[c];
            float t  = is_high ? ((m > 0.f) ? m * whv : m * wlv) : ((m > 0.f) ? m * wlv : m * whv);
            float bt = is_high ? fmaxf(m, 0.f) * bhv : fminf(m, 0.f) * bhv;
            acc += bt + t * b0[c];
        }
    }
    float2 rr = blockReduce256x2(acc, accx);
    if (threadIdx.x == 0) {
        bias20[row] = b4[srow] + rr.x;
        if (is_high) out[row] = b4[row] + rr.y;
    }
}

// Final layer-4 interval matvec from 8 split-K parts.
__global__ void k_fbox20(const float* __restrict__ Ppart,
                         const float* __restrict__ bias20,
                         const float* __restrict__ lo0, const float* __restrict__ hi0,
                         float* __restrict__ out) {
    int row = blockIdx.x;
    int is_high = row < 10;
    float acc = 0.f;
    for (int c = threadIdx.x; c < 784; c += 256) {
        float m = 0.f;
        #pragma unroll
        for (int p = 0; p < 8; p++)
            m += Ppart[(size_t)p * 40960 + (size_t)row * 2048 + c];
        if (is_high) acc += (m < 0.f) ? m * lo0[c] : m * hi0[c];
        else         acc += (m < 0.f) ? m * hi0[c] : m * lo0[c];
    }
    acc = blockReduce256(acc);
    if (threadIdx.x == 0) {
        float v = acc + bias20[row];
        out[is_high ? (20 + row) : row] = v;
    }
}

extern "C" void kernel_launch(void* const* d_in, const int* in_sizes, int n_in,
                              void* d_out, int out_size, void* d_ws, size_t ws_size,
                              hipStream_t stream) {
    const float* x_in  = (const float*)d_in[0];
    const float* lo_in = (const float*)d_in[1];
    const float* hi_in = (const float*)d_in[2];
    const float* W[5];
    const float* bv[5];
    for (int i = 0; i < 5; i++) {
        W[i]  = (const float*)d_in[3 + 2 * i];
        bv[i] = (const float*)d_in[4 + 2 * i];
    }
    float* ws = (float*)d_ws;
    float* out = (float*)d_out;

    float* X[2]    = {ws + OFF_X0, ws + OFF_X1};
    float* lo0     = ws + OFF_L0;
    float* hi0     = ws + OFF_H0;
    float* BOX[2]  = {ws + OFF_BOXA, ws + OFF_BOXB};
    float* BIAS[2] = {ws + OFF_BIASA, ws + OFF_BIASB};
    float* b20     = ws + OFF_B20;
    float* PPa     = ws + OFF_PPA;
    float* PPb     = ws + OFF_PPB;
    float* PPc     = ws + OFF_PPC;
    float* PPd     = ws + OFF_PPD;
    _Float16* WT_H[3] = {(_Float16*)(ws + OFF_W0TH), (_Float16*)(ws + OFF_W1TH),
                         (_Float16*)(ws + OFF_W2TH)};
    _Float16* WT_L[3] = {(_Float16*)(ws + OFF_W0TL), (_Float16*)(ws + OFF_W1TL),
                         (_Float16*)(ws + OFF_W2TL)};
    _Float16* AH[2] = {(_Float16*)(ws + OFF_AH0), (_Float16*)(ws + OFF_AH1)};
    _Float16* AL[2] = {(_Float16*)(ws + OFF_AL0), (_Float16*)(ws + OFF_AL1)};
    float* WLr = ws + OFF_WL;
    float* WHr = ws + OFF_WH;
    float* BHr = ws + OFF_BHR;

    k_norm<<<4, 256, 0, stream>>>(x_in, lo_in, hi_in, ws);
    // hoisted transposes (input-only dependencies)
    k_transpose_split<<<dim3(28, 64), 256, 0, stream>>>(W[0], 784, WT_H[0], WT_L[0]);
    k_transpose_split<<<dim3(64, 64), 256, 0, stream>>>(W[1], 2048, WT_H[1], WT_L[1]);
    k_transpose_split<<<dim3(64, 64), 256, 0, stream>>>(W[2], 2048, WT_H[2], WT_L[2]);

    // ---- layer 0 ----
    k_fboxes0<<<4096, 256, 0, stream>>>(W[0], bv[0], X[0], lo0, hi0, BOX[0], X[1]);

    // ---- layers 1..3 ----
    int xcur = 1, bprev = 0;   // BOX[bprev] = prev layer bounds; bias ping-pong
    const float* biasPrev = nullptr;
    for (int i = 1; i <= 3; i++) {
        int xnxt = xcur ^ 1;
        int bcur = bprev ^ 1;
        float* biasCur = BIAS[(i - 1) & 1];
        k_relu_split<<<4096, 256, 0, stream>>>(
            W[i], X[xcur], BOX[bprev], biasPrev,
            WLr + (i - 1) * 2048, WHr + (i - 1) * 2048, BHr + (i - 1) * 2048,
            bv[i - 1], bv[i], biasCur, BOX[bcur], X[xnxt], AH[0], AL[0]);
        int p = 0;
        for (int j = i - 1; j >= 1; j--) {
            k_gemm<4, 0><<<dim3(16, 32), 256, 0, stream>>>(
                AH[p], AL[p], WT_H[j], WT_L[j],
                WLr + (j - 1) * 2048, WHr + (j - 1) * 2048,
                BHr + (j - 1) * 2048, bv[j - 1], biasCur,
                AH[p ^ 1], AL[p ^ 1], nullptr, nullptr, nullptr);
            p ^= 1;
        }
        k_gemm<2, 1><<<dim3(14, 32), 256, 0, stream>>>(
            AH[p], AL[p], WT_H[0], WT_L[0],
            nullptr, nullptr, nullptr, nullptr, nullptr,
            nullptr, nullptr, lo0, hi0, BOX[bcur]);
        biasPrev = biasCur;
        bprev = bcur;
        xcur = xnxt;
    }
    // rec3 for the layer-4 path (BIAS[(3-1)&1] = BIAS[0])
    k_relu_rec<<<8, 256, 0, stream>>>(BOX[bprev], BIAS[0],
                                      WLr + 3 * 2048, WHr + 3 * 2048, BHr + 3 * 2048);

    // ---- layer 4: 20-row chains (split-K partial path) ----
    k_skinny2<<<dim3(16, 8), 256, 0, stream>>>(W[4], 1,
        WLr + 3 * 2048, WHr + 3 * 2048, W[3], 2048, PPa);
    k_skinny2<<<dim3(16, 8), 256, 0, stream>>>(PPa, 0,
        WLr + 2 * 2048, WHr + 2 * 2048, W[2], 2048, PPb);
    k_skinny2<<<dim3(16, 8), 256, 0, stream>>>(PPb, 0,
        WLr + 1 * 2048, WHr + 1 * 2048, W[1], 2048, PPc);
    k_skinny2<<<dim3(7, 8), 256, 0, stream>>>(PPc, 0,
        WLr, WHr, W[0], 784, PPd);
    k_bias20<<<20, 256, 0, stream>>>(W[4], PPa, PPb, PPc,
        WLr, WHr, BHr, bv[0], bv[1], bv[2], bv[3], bv[4], X[xcur], b20, out);
    k_fbox20<<<20, 256, 0, stream>>>(PPd, b20, lo0, hi0, out);
}

// Round 14
// 783.202 us; speedup vs baseline: 1.1598x; 1.0718x over previous
//
#include <hip/hip_runtime.h>
#include <hip/hip_bf16.h>

// DeepPoly MLP verifier (784->2048x4->10).
// Round 19: GEMMs locked at the r15 configuration (reproduced 839us;
// best 829). This round targets the two provable occupancy holes in the
// non-GEMM dispatches:
//  1) k_skinny2: grid (16,8)=128 blocks -> HALF the CUs idle while
//     streaming 16MB of W. Now 64-wide cols x 4-way K-half: (32,8)=256
//     blocks, same work, same partial layout.
//  2) k_bias20: 20 blocks -> 20/256 CUs. Now 8 c-chunks x 20 rows = 160
//     blocks, block-reduce + atomicAdd; bias20/out pre-seeded with b4 in
//     k_relu_rec (runs immediately before).
// GEMM kernels byte-identical to r15 (control group for counters).

#define MEAN_C 0.1307f
#define STD_C  0.3081f

// ---- workspace offsets (floats), total ~108.2 MB ----
#define OFF_X0     0u
#define OFF_X1     2048u
#define OFF_L0     4096u       // 896 used (zero-padded)
#define OFF_H0     5120u
#define OFF_WL     6144u       // 4*2048 (rec j at +j*2048)
#define OFF_WH     14336u
#define OFF_BHR    22528u
#define OFF_BOXA   30720u      // 4096
#define OFF_BOXB   34816u
#define OFF_BIASA  38912u      // 4096
#define OFF_BIASB  43008u
#define OFF_B20    47104u      // 32
#define OFF_W0TH   47136u      // f16 [896][2048]  = 917504 float-slots
#define OFF_W0TL   964640u
#define OFF_W1TH   1882144u    // f16 [2048][2048] = 2097152 float-slots
#define OFF_W1TL   3979296u
#define OFF_W2TH   6076448u
#define OFF_W2TL   8173600u
#define OFF_AH0    10270752u   // f16 [4096][2048] = 4194304 float-slots
#define OFF_AL0    14465056u
#define OFF_AH1    18659360u
#define OFF_AL1    22853664u
// PP split-K partials alias into AH1 (free during layer 4): 4 x 327680 floats
#define OFF_PPA    18659360u
#define OFF_PPB    18987040u
#define OFF_PPC    19314720u
#define OFF_PPD    19642400u
// end 27047968 floats

typedef _Float16 half8 __attribute__((ext_vector_type(8)));
typedef float floatx4 __attribute__((ext_vector_type(4)));

__device__ __forceinline__ void gl2lds16(const void* g, void* l) {
    __builtin_amdgcn_global_load_lds(
        (const __attribute__((address_space(1))) unsigned int*)g,
        (__attribute__((address_space(3))) unsigned int*)l, 16, 0, 0);
}

__device__ __forceinline__ float blockReduce256(float v) {
    #pragma unroll
    for (int o = 32; o > 0; o >>= 1) v += __shfl_down(v, o, 64);
    __shared__ float sred[4];
    int w = threadIdx.x >> 6;
    if ((threadIdx.x & 63) == 0) sred[w] = v;
    __syncthreads();
    float r = 0.f;
    if (threadIdx.x == 0) r = sred[0] + sred[1] + sred[2] + sred[3];
    return r;
}

__device__ __forceinline__ float2 blockReduce256x2(float a, float b) {
    #pragma unroll
    for (int o = 32; o > 0; o >>= 1) {
        a += __shfl_down(a, o, 64);
        b += __shfl_down(b, o, 64);
    }
    __shared__ float sa[4], sb[4];
    int w = threadIdx.x >> 6;
    if ((threadIdx.x & 63) == 0) { sa[w] = a; sb[w] = b; }
    __syncthreads();
    float2 r = {0.f, 0.f};
    if (threadIdx.x == 0) {
        r.x = sa[0] + sa[1] + sa[2] + sa[3];
        r.y = sb[0] + sb[1] + sb[2] + sb[3];
    }
    return r;
}

// DeepPoly relu relaxation from bounds (h,l).
__device__ __forceinline__ void relu_rec_calc(float h, float l,
                                              float& vwl, float& vwh, float& vbh) {
    if (h <= 0.f)      { vwl = 0.f; vwh = 0.f; vbh = 0.f; }
    else if (l >= 0.f) { vwl = 1.f; vwh = 1.f; vbh = 0.f; }
    else {
        float d = h - l;
        vwh = h / d;
        vbh = -(l * h) / d;
        vwl = (l * l > h * h) ? 0.f : 1.f;
    }
}

__global__ void k_norm(const float* __restrict__ x, const float* __restrict__ lo,
                       const float* __restrict__ hi, float* __restrict__ ws) {
    int i = blockIdx.x * blockDim.x + threadIdx.x;
    if (i < 784) {
        ws[OFF_X0 + i] = (x[i]  - MEAN_C) / STD_C;
        ws[OFF_L0 + i] = (lo[i] - MEAN_C) / STD_C;
        ws[OFF_H0 + i] = (hi[i] - MEAN_C) / STD_C;
    } else if (i < 896) {
        ws[OFF_L0 + i] = 0.f;
        ws[OFF_H0 + i] = 0.f;
    }
}

// Layer-0 interval matvec + forward matvec fused.
__global__ void k_fboxes0(const float* __restrict__ W0, const float* __restrict__ b0,
                          const float* __restrict__ x0,
                          const float* __restrict__ lo0, const float* __restrict__ hi0,
                          float* __restrict__ box, float* __restrict__ xout) {
    int r = blockIdx.x;
    int srow = r & 2047;
    int is_high = r < 2048;
    const float* Wr = W0 + (size_t)srow * 784;
    float acc = 0.f, accx = 0.f;
    for (int c = threadIdx.x; c < 784; c += 256) {
        float m = Wr[c];
        if (is_high) acc += (m < 0.f) ? m * lo0[c] : m * hi0[c];
        else         acc += (m < 0.f) ? m * hi0[c] : m * lo0[c];
        accx += m * x0[c];
    }
    float2 rr = blockReduce256x2(acc, accx);
    if (threadIdx.x == 0) {
        box[r] = rr.x + b0[srow];
        if (is_high) xout[r] = rr.y + b0[r];
    }
}

// First backsub step of layer i, with INLINE relu-record computation from
// (boxPrev, biasPrev): T_{i-1}(W_i) stacked (4096 rows) -> f16 hi/lo A;
// bias = bv_i + (bhr dot + T@b_{i-1}); block 0 materializes rec arrays;
// thread 0 zeroes boxOut[row]; rows<2048 also compute y = W_i@relu(x)+bv_i.
__global__ __launch_bounds__(256) void k_relu_split(
        const float* __restrict__ Wi, const float* __restrict__ xin,
        const float* __restrict__ boxPrev, const float* __restrict__ biasPrev,
        float* __restrict__ recWL, float* __restrict__ recWH, float* __restrict__ recBH,
        const float* __restrict__ bj, const float* __restrict__ bvi,
        float* __restrict__ bias, float* __restrict__ boxOut,
        float* __restrict__ xout,
        _Float16* __restrict__ Ahi, _Float16* __restrict__ Alo) {
    int row = blockIdx.x;
    int is_high = row < 2048;
    int srow = row & 2047;
    const float* src = Wi + (size_t)srow * 2048;
    int c0 = threadIdx.x * 8;
    float mv[8], bxh[8], bxl[8], abj[8], ax[8];
    *(float4*)&mv[0]  = *(const float4*)(src + c0);
    *(float4*)&mv[4]  = *(const float4*)(src + c0 + 4);
    *(float4*)&bxh[0] = *(const float4*)(boxPrev + c0);
    *(float4*)&bxh[4] = *(const float4*)(boxPrev + c0 + 4);
    *(float4*)&bxl[0] = *(const float4*)(boxPrev + 2048 + c0);
    *(float4*)&bxl[4] = *(const float4*)(boxPrev + 2048 + c0 + 4);
    *(float4*)&abj[0] = *(const float4*)(bj + c0);
    *(float4*)&abj[4] = *(const float4*)(bj + c0 + 4);
    *(float4*)&ax[0]  = *(const float4*)(xin + c0);
    *(float4*)&ax[4]  = *(const float4*)(xin + c0 + 4);
    if (biasPrev) {
        float ph[8], pl[8];
        *(float4*)&ph[0] = *(const float4*)(biasPrev + c0);
        *(float4*)&ph[4] = *(const float4*)(biasPrev + c0 + 4);
        *(float4*)&pl[0] = *(const float4*)(biasPrev + 2048 + c0);
        *(float4*)&pl[4] = *(const float4*)(biasPrev + 2048 + c0 + 4);
        #pragma unroll
        for (int e = 0; e < 8; e++) { bxh[e] += ph[e]; bxl[e] += pl[e]; }
    }
    float acc = 0.f, accx = 0.f;
    float rl[8], rh[8], rb[8];
    half8 hi, lo;
    #pragma unroll
    for (int e = 0; e < 8; e++) {
        relu_rec_calc(bxh[e], bxl[e], rl[e], rh[e], rb[e]);
        float m = mv[e];
        float t, bt;
        if (is_high) { t = (m > 0.f) ? m * rh[e] : m * rl[e]; bt = fmaxf(m, 0.f) * rb[e]; }
        else         { t = (m > 0.f) ? m * rl[e] : m * rh[e]; bt = fminf(m, 0.f) * rb[e]; }
        acc += bt + t * abj[e];
        accx += m * fmaxf(ax[e], 0.f);
        _Float16 h = (_Float16)t;
        hi[e] = h;
        lo[e] = (_Float16)(t - (float)h);
    }
    *(half8*)(Ahi + (size_t)row * 2048 + c0) = hi;
    *(half8*)(Alo + (size_t)row * 2048 + c0) = lo;
    if (row == 0) {   // materialize rec arrays for later consumers
        *(float4*)(recWL + c0) = *(float4*)&rl[0];
        *(float4*)(recWL + c0 + 4) = *(float4*)&rl[4];
        *(float4*)(recWH + c0) = *(float4*)&rh[0];
        *(float4*)(recWH + c0 + 4) = *(float4*)&rh[4];
        *(float4*)(recBH + c0) = *(float4*)&rb[0];
        *(float4*)(recBH + c0 + 4) = *(float4*)&rb[4];
    }
    float2 rr = blockReduce256x2(acc, accx);
    if (threadIdx.x == 0) {
        bias[row] = bvi[srow] + rr.x;
        boxOut[row] = 0.f;
        if (is_high) xout[row] = rr.y + bvi[row];
    }
}

// Transpose + f16 hi/lo split: Wt[n][k] = W[k][n]; pad n in [NC,NP) with 0.
__global__ void k_transpose_split(const float* __restrict__ W, int NC,
                                  _Float16* __restrict__ Thi,
                                  _Float16* __restrict__ Tlo) {
    __shared__ float s[32][33];
    int c = threadIdx.x & 31;
    int r = threadIdx.x >> 5;
    #pragma unroll
    for (int rr = 0; rr < 4; rr++) {
        int k = blockIdx.y * 32 + r + rr * 8;
        int n = blockIdx.x * 32 + c;
        float v = (n < NC) ? W[(size_t)k * NC + n] : 0.f;
        s[c][r + rr * 8] = v;
    }
    __syncthreads();
    #pragma unroll
    for (int rr = 0; rr < 4; rr++) {
        int nl = r + rr * 8;
        float v = s[nl][c];
        _Float16 h = (_Float16)v;
        size_t o = (size_t)(blockIdx.x * 32 + nl) * 2048 + blockIdx.y * 32 + c;
        Thi[o] = h;
        Tlo[o] = (_Float16)(v - (float)h);
    }
}

// C[4096,NP] = (Ah+Al) @ (Bh+Bl)^T, 3 f16 products. BM=128, BN=NT*32,
// BK=32; 256 threads. Depth-2 counted-vmcnt pipeline (r9) + T5 setprio
// (r11) + XCD-aware block swizzle (r15). UNCHANGED from r15.
// EPI 0: relu-backsub epilogue (emit next Ah/Al + bias atomics).
// EPI 1: interval-matvec epilogue (atomics into pre-zeroed BOX).
template<int NT, int EPI>
__global__ __launch_bounds__(256, 2) void k_gemm(
        const _Float16* __restrict__ Ah, const _Float16* __restrict__ Al,
        const _Float16* __restrict__ Bh, const _Float16* __restrict__ Bl,
        const float* __restrict__ wl, const float* __restrict__ wh,
        const float* __restrict__ bhr, const float* __restrict__ bj,
        float* __restrict__ bias,
        _Float16* __restrict__ oAh, _Float16* __restrict__ oAl,
        const float* __restrict__ lo0, const float* __restrict__ hi0,
        float* __restrict__ box) {
    __shared__ _Float16 sAh[2][128 * 32], sAl[2][128 * 32];
    __shared__ _Float16 sBh[2][NT * 32 * 32], sBl[2][NT * 32 * 32];
    int tid = threadIdx.x;

    // XCD-aware swizzle: nwg (512 or 448) is divisible by 8 -> bijective.
    int gx = gridDim.x;
    int bid = blockIdx.y * gx + blockIdx.x;
    int cpx = (gx * gridDim.y) >> 3;
    int l   = (bid & 7) * cpx + (bid >> 3);
    int bx  = l % gx;
    int by  = l / gx;
    int row0 = by * 128, col0 = bx * (NT * 32);

    int cr = tid >> 2;
    int q  = (tid & 3) ^ ((cr >> 1) & 3);   // bank swizzle at fetch (keyed on row>>1)
    const _Float16* gAh0 = Ah + (size_t)(row0 + cr) * 2048 + q * 8;
    const _Float16* gAh1 = gAh0 + (size_t)64 * 2048;
    const _Float16* gAl0 = Al + (size_t)(row0 + cr) * 2048 + q * 8;
    const _Float16* gAl1 = gAl0 + (size_t)64 * 2048;
    const _Float16* gBh0 = Bh + (size_t)(col0 + cr) * 2048 + q * 8;
    const _Float16* gBl0 = Bl + (size_t)(col0 + cr) * 2048 + q * 8;
    const _Float16* gBh1 = gBh0 + (size_t)64 * 2048;   // NT==4 only
    const _Float16* gBl1 = gBl0 + (size_t)64 * 2048;
    int loff = tid * 8;

    int lane = tid & 63, wv = tid >> 6;
    int wm = wv & 1, wn = wv >> 1;
    int l15 = lane & 15, lq = lane >> 4;
    int soff = (lq ^ ((l15 >> 1) & 3)) * 8;  // matches write-side swizzle
    int arow = wm * 64 + l15;
    int brow = wn * (NT * 16) + l15;

    floatx4 acc[4][NT];
    floatx4 z = {0.f, 0.f, 0.f, 0.f};
    #pragma unroll
    for (int i = 0; i < 4; i++)
        #pragma unroll
        for (int j = 0; j < NT; j++) acc[i][j] = z;

    // per-wave loads per K-tile: NT==4 -> 8, NT==2 -> 6
    auto STAGE = [&](int b, int k0) {
        gl2lds16(gAh0 + k0, &sAh[b][loff]);
        gl2lds16(gAh1 + k0, &sAh[b][loff + 2048]);
        gl2lds16(gAl0 + k0, &sAl[b][loff]);
        gl2lds16(gAl1 + k0, &sAl[b][loff + 2048]);
        gl2lds16(gBh0 + k0, &sBh[b][loff]);
        gl2lds16(gBl0 + k0, &sBl[b][loff]);
        if (NT == 4) {
            gl2lds16(gBh1 + k0, &sBh[b][loff + 2048]);
            gl2lds16(gBl1 + k0, &sBl[b][loff + 2048]);
        }
    };

    STAGE(0, 0);
    STAGE(1, 32);
    if constexpr (NT == 4) asm volatile("s_waitcnt vmcnt(8)" ::: "memory");
    else                   asm volatile("s_waitcnt vmcnt(6)" ::: "memory");
    __builtin_amdgcn_s_barrier();
    __builtin_amdgcn_sched_barrier(0);

    for (int t = 0; t < 64; ++t) {
        int cur = t & 1;
        half8 bh[NT], bl[NT], ah4[4], al4[4];
        #pragma unroll
        for (int nt = 0; nt < NT; nt++) {
            bh[nt] = *(const half8*)&sBh[cur][(brow + nt * 16) * 32 + soff];
            bl[nt] = *(const half8*)&sBl[cur][(brow + nt * 16) * 32 + soff];
        }
        #pragma unroll
        for (int mt = 0; mt < 4; mt++) {
            ah4[mt] = *(const half8*)&sAh[cur][(arow + mt * 16) * 32 + soff];
            al4[mt] = *(const half8*)&sAl[cur][(arow + mt * 16) * 32 + soff];
        }
        // all reads of buf[cur] retired before anyone overwrites it
        asm volatile("s_waitcnt lgkmcnt(0)" ::: "memory");
        __builtin_amdgcn_sched_barrier(0);
        __builtin_amdgcn_s_barrier();
        __builtin_amdgcn_sched_barrier(0);
        if (t < 62) STAGE(cur, (t + 2) * 32);   // overwrite buf[cur] for t+2
        __builtin_amdgcn_s_setprio(1);
        #pragma unroll
        for (int mt = 0; mt < 4; mt++) {
            #pragma unroll
            for (int nt = 0; nt < NT; nt++) {
                acc[mt][nt] = __builtin_amdgcn_mfma_f32_16x16x32_f16(ah4[mt], bh[nt], acc[mt][nt], 0, 0, 0);
                acc[mt][nt] = __builtin_amdgcn_mfma_f32_16x16x32_f16(al4[mt], bh[nt], acc[mt][nt], 0, 0, 0);
                acc[mt][nt] = __builtin_amdgcn_mfma_f32_16x16x32_f16(ah4[mt], bl[nt], acc[mt][nt], 0, 0, 0);
            }
        }
        __builtin_amdgcn_s_setprio(0);
        if (t < 63) {
            if (t < 62) {   // wait tile t+1 only; t+2's loads stay in flight
                if constexpr (NT == 4) asm volatile("s_waitcnt vmcnt(8)" ::: "memory");
                else                   asm volatile("s_waitcnt vmcnt(6)" ::: "memory");
            } else {        // pipeline drain before the final tile
                asm volatile("s_waitcnt vmcnt(0)" ::: "memory");
            }
            __builtin_amdgcn_s_barrier();
            __builtin_amdgcn_sched_barrier(0);
        }
    }

    // C/D layout: col = lane&15, row = (lane>>4)*4 + reg
    int is_high = row0 < 2048;
    float bsum[4][4];
    #pragma unroll
    for (int mt = 0; mt < 4; mt++)
        #pragma unroll
        for (int r = 0; r < 4; r++) bsum[mt][r] = 0.f;

    #pragma unroll
    for (int nt = 0; nt < NT; nt++) {
        int gc = col0 + wn * (NT * 16) + nt * 16 + l15;
        if (EPI == 0) {
            float cwl = wl[gc], cwh = wh[gc], cbh = bhr[gc], cbj = bj[gc];
            #pragma unroll
            for (int mt = 0; mt < 4; mt++) {
                #pragma unroll
                for (int r = 0; r < 4; r++) {
                    float m = acc[mt][nt][r];
                    float t, bt;
                    if (is_high) { t = (m > 0.f) ? m * cwh : m * cwl; bt = fmaxf(m, 0.f) * cbh; }
                    else         { t = (m > 0.f) ? m * cwl : m * cwh; bt = fminf(m, 0.f) * cbh; }
                    bsum[mt][r] += bt + t * cbj;
                    int grow = row0 + wm * 64 + mt * 16 + lq * 4 + r;
                    size_t o = (size_t)grow * 2048 + gc;
                    _Float16 h = (_Float16)t;
                    oAh[o] = h;
                    oAl[o] = (_Float16)(t - (float)h);
                }
            }
        } else {
            float clo = lo0[gc], chi = hi0[gc];
            #pragma unroll
            for (int mt = 0; mt < 4; mt++) {
                #pragma unroll
                for (int r = 0; r < 4; r++) {
                    float m = acc[mt][nt][r];
                    float contrib;
                    if (is_high) contrib = (m < 0.f) ? m * clo : m * chi;
                    else         contrib = (m < 0.f) ? m * chi : m * clo;
                    bsum[mt][r] += contrib;
                }
            }
        }
    }
    #pragma unroll
    for (int mt = 0; mt < 4; mt++) {
        #pragma unroll
        for (int r = 0; r < 4; r++) {
            float v = bsum[mt][r];
            v += __shfl_xor(v, 1);
            v += __shfl_xor(v, 2);
            v += __shfl_xor(v, 4);
            v += __shfl_xor(v, 8);
            if (l15 == 0) {
                int grow = row0 + wm * 64 + mt * 16 + lq * 4 + r;
                if (EPI == 0) atomicAdd(&bias[grow], v);
                else          atomicAdd(&box[grow], v);
            }
        }
    }
}

// Rec3 capture + seed bias20/out with b4 for the atomic k_bias20.
__global__ void k_relu_rec(const float* __restrict__ box, const float* __restrict__ bias,
                           float* __restrict__ wl, float* __restrict__ wh,
                           float* __restrict__ bhr,
                           float* __restrict__ bias20, float* __restrict__ out,
                           const float* __restrict__ b4) {
    int i = blockIdx.x * blockDim.x + threadIdx.x;
    float h = box[i] + bias[i];
    float l = box[2048 + i] + bias[2048 + i];
    float vwl, vwh, vbh;
    relu_rec_calc(h, l, vwl, vwh, vbh);
    wl[i] = vwl; wh[i] = vwh; bhr[i] = vbh;
    if (blockIdx.x == 0) {
        int t = threadIdx.x;
        if (t < 20)      bias20[t] = b4[t % 10];   // base for atomic sums
        else if (t < 30) out[t - 20] = b4[t - 20]; // out[0..9] base
    }
}

// Layer-4 fused: reduce prev partials (or W4 bcast) + relu-backsub transform
// in prologue, then split-K skinny GEMM. Rows 0..9 high, 10..19 low.
// r19: 64-wide columns x 4-way K-half -> grid (32,8)/(13,8) = full GPU.
__global__ __launch_bounds__(256) void k_skinny2(
        const float* __restrict__ src, int bcast,
        const float* __restrict__ wl, const float* __restrict__ wh,
        const float* __restrict__ W, int N, float* __restrict__ Ppart) {
    __shared__ float sA[20 * 256];
    __shared__ float sRed[20 * 192];
    int ky = blockIdx.y, k0 = ky * 256;
    int tid = threadIdx.x;
    for (int idx = tid; idx < 20 * 256; idx += 256) {
        int r = idx >> 8, c = idx & 255;
        int gc = k0 + c;
        float m;
        if (bcast) m = src[(size_t)(r % 10) * 2048 + gc];
        else {
            m = 0.f;
            #pragma unroll
            for (int p = 0; p < 8; p++)
                m += src[(size_t)p * 40960 + (size_t)r * 2048 + gc];
        }
        float t = (r < 10) ? ((m > 0.f) ? m * wh[gc] : m * wl[gc])
                           : ((m > 0.f) ? m * wl[gc] : m * wh[gc]);
        sA[idx] = t;
    }
    __syncthreads();
    int c = blockIdx.x * 64 + (tid & 63);
    int kh = tid >> 6;   // 0..3, each covers 64 of the 256 K-chunk
    float acc[20];
    #pragma unroll
    for (int r = 0; r < 20; r++) acc[r] = 0.f;
    if (c < N) {
        const float* Wp = W + (size_t)(k0 + kh * 64) * N + c;
        for (int kk = 0; kk < 64; kk++) {
            float w = Wp[(size_t)kk * N];
            #pragma unroll
            for (int r = 0; r < 20; r++) acc[r] += sA[r * 256 + kh * 64 + kk] * w;
        }
    }
    if (kh > 0 && c < N) {
        #pragma unroll
        for (int r = 0; r < 20; r++)
            sRed[r * 192 + (kh - 1) * 64 + (tid & 63)] = acc[r];
    }
    __syncthreads();
    if (kh == 0 && c < N) {
        #pragma unroll
        for (int r = 0; r < 20; r++)
            Ppart[(size_t)ky * 40960 + (size_t)r * 2048 + c] =
                acc[r] + sRed[r * 192 + (tid & 63)]
                       + sRed[r * 192 + 64 + (tid & 63)]
                       + sRed[r * 192 + 128 + (tid & 63)];
    }
}

// All four layer-4 bias dots + the forward matvec (out[0..9]).
// r19: grid (8 c-chunks, 20 rows); block-reduce + atomicAdd onto the
// b4-seeded bias20/out (seeded in k_relu_rec).
__global__ void k_bias20(const float* __restrict__ W4,
                         const float* __restrict__ PPa, const float* __restrict__ PPb,
                         const float* __restrict__ PPc,
                         const float* __restrict__ WLr, const float* __restrict__ WHr,
                         const float* __restrict__ BHr,
                         const float* __restrict__ b0, const float* __restrict__ b1,
                         const float* __restrict__ b2, const float* __restrict__ b3,
                         const float* __restrict__ x3,
                         float* __restrict__ bias20, float* __restrict__ out) {
    int row = blockIdx.y;
    int is_high = row < 10;
    int srow = row % 10;
    int c = blockIdx.x * 256 + threadIdx.x;
    float acc = 0.f, accx = 0.f;
    {
        {   // rec3 on W4 (+ forward matvec with relu'd x3)
            float m = W4[(size_t)srow * 2048 + c];
            float wlv = WLr[3 * 2048 + c], whv = WHr[3 * 2048 + c], bhv = BHr[3 * 2048 + c];
            float t  = is_high ? ((m > 0.f) ? m * whv : m * wlv) : ((m > 0.f) ? m * wlv : m * whv);
            float bt = is_high ? fmaxf(m, 0.f) * bhv : fminf(m, 0.f) * bhv;
            acc += bt + t * b3[c];
            accx += m * fmaxf(x3[c], 0.f);
        }
        {   // rec2 on sum PPa
            float m = 0.f;
            #pragma unroll
            for (int p = 0; p < 8; p++) m += PPa[(size_t)p * 40960 + (size_t)row * 2048 + c];
            float wlv = WLr[2 * 2048 + c], whv = WHr[2 * 2048 + c], bhv = BHr[2 * 2048 + c];
            float t  = is_high ? ((m > 0.f) ? m * whv : m * wlv) : ((m > 0.f) ? m * wlv : m * whv);
            float bt = is_high ? fmaxf(m, 0.f) * bhv : fminf(m, 0.f) * bhv;
            acc += bt + t * b2[c];
        }
        {   // rec1 on sum PPb
            float m = 0.f;
            #pragma unroll
            for (int p = 0; p < 8; p++) m += PPb[(size_t)p * 40960 + (size_t)row * 2048 + c];
            float wlv = WLr[1 * 2048 + c], whv = WHr[1 * 2048 + c], bhv = BHr[1 * 2048 + c];
            float t  = is_high ? ((m > 0.f) ? m * whv : m * wlv) : ((m > 0.f) ? m * wlv : m * whv);
            float bt = is_high ? fmaxf(m, 0.f) * bhv : fminf(m, 0.f) * bhv;
            acc += bt + t * b1[c];
        }
        {   // rec0 on sum PPc
            float m = 0.f;
            #pragma unroll
            for (int p = 0; p < 8; p++) m += PPc[(size_t)p * 40960 + (size_t)row * 2048 + c];
            float wlv = WLr[c], whv = WHr[c], bhv = BHr[c];
            float t  = is_high ? ((m > 0.f) ? m * whv : m * wlv) : ((m > 0.f) ? m * wlv : m * whv);
            float bt = is_high ? fmaxf(m, 0.f) * bhv : fminf(m, 0.f) * bhv;
            acc += bt + t * b0[c];
        }
    }
    float2 rr = blockReduce256x2(acc, accx);
    if (threadIdx.x == 0) {
        atomicAdd(&bias20[row], rr.x);
        if (is_high) atomicAdd(&out[row], rr.y);
    }
}

// Final layer-4 interval matvec from 8 split-K parts.
__global__ void k_fbox20(const float* __restrict__ Ppart,
                         const float* __restrict__ bias20,
                         const float* __restrict__ lo0, const float* __restrict__ hi0,
                         float* __restrict__ out) {
    int row = blockIdx.x;
    int is_high = row < 10;
    float acc = 0.f;
    for (int c = threadIdx.x; c < 784; c += 256) {
        float m = 0.f;
        #pragma unroll
        for (int p = 0; p < 8; p++)
            m += Ppart[(size_t)p * 40960 + (size_t)row * 2048 + c];
        if (is_high) acc += (m < 0.f) ? m * lo0[c] : m * hi0[c];
        else         acc += (m < 0.f) ? m * hi0[c] : m * lo0[c];
    }
    acc = blockReduce256(acc);
    if (threadIdx.x == 0) {
        float v = acc + bias20[row];
        out[is_high ? (20 + row) : row] = v;
    }
}

extern "C" void kernel_launch(void* const* d_in, const int* in_sizes, int n_in,
                              void* d_out, int out_size, void* d_ws, size_t ws_size,
                              hipStream_t stream) {
    const float* x_in  = (const float*)d_in[0];
    const float* lo_in = (const float*)d_in[1];
    const float* hi_in = (const float*)d_in[2];
    const float* W[5];
    const float* bv[5];
    for (int i = 0; i < 5; i++) {
        W[i]  = (const float*)d_in[3 + 2 * i];
        bv[i] = (const float*)d_in[4 + 2 * i];
    }
    float* ws = (float*)d_ws;
    float* out = (float*)d_out;

    float* X[2]    = {ws + OFF_X0, ws + OFF_X1};
    float* lo0     = ws + OFF_L0;
    float* hi0     = ws + OFF_H0;
    float* BOX[2]  = {ws + OFF_BOXA, ws + OFF_BOXB};
    float* BIAS[2] = {ws + OFF_BIASA, ws + OFF_BIASB};
    float* b20     = ws + OFF_B20;
    float* PPa     = ws + OFF_PPA;
    float* PPb     = ws + OFF_PPB;
    float* PPc     = ws + OFF_PPC;
    float* PPd     = ws + OFF_PPD;
    _Float16* WT_H[3] = {(_Float16*)(ws + OFF_W0TH), (_Float16*)(ws + OFF_W1TH),
                         (_Float16*)(ws + OFF_W2TH)};
    _Float16* WT_L[3] = {(_Float16*)(ws + OFF_W0TL), (_Float16*)(ws + OFF_W1TL),
                         (_Float16*)(ws + OFF_W2TL)};
    _Float16* AH[2] = {(_Float16*)(ws + OFF_AH0), (_Float16*)(ws + OFF_AH1)};
    _Float16* AL[2] = {(_Float16*)(ws + OFF_AL0), (_Float16*)(ws + OFF_AL1)};
    float* WLr = ws + OFF_WL;
    float* WHr = ws + OFF_WH;
    float* BHr = ws + OFF_BHR;

    k_norm<<<4, 256, 0, stream>>>(x_in, lo_in, hi_in, ws);
    // hoisted transposes (input-only dependencies)
    k_transpose_split<<<dim3(28, 64), 256, 0, stream>>>(W[0], 784, WT_H[0], WT_L[0]);
    k_transpose_split<<<dim3(64, 64), 256, 0, stream>>>(W[1], 2048, WT_H[1], WT_L[1]);
    k_transpose_split<<<dim3(64, 64), 256, 0, stream>>>(W[2], 2048, WT_H[2], WT_L[2]);

    // ---- layer 0 ----
    k_fboxes0<<<4096, 256, 0, stream>>>(W[0], bv[0], X[0], lo0, hi0, BOX[0], X[1]);

    // ---- layers 1..3 ----
    int xcur = 1, bprev = 0;   // BOX[bprev] = prev layer bounds; bias ping-pong
    const float* biasPrev = nullptr;
    for (int i = 1; i <= 3; i++) {
        int xnxt = xcur ^ 1;
        int bcur = bprev ^ 1;
        float* biasCur = BIAS[(i - 1) & 1];
        k_relu_split<<<4096, 256, 0, stream>>>(
            W[i], X[xcur], BOX[bprev], biasPrev,
            WLr + (i - 1) * 2048, WHr + (i - 1) * 2048, BHr + (i - 1) * 2048,
            bv[i - 1], bv[i], biasCur, BOX[bcur], X[xnxt], AH[0], AL[0]);
        int p = 0;
        for (int j = i - 1; j >= 1; j--) {
            k_gemm<4, 0><<<dim3(16, 32), 256, 0, stream>>>(
                AH[p], AL[p], WT_H[j], WT_L[j],
                WLr + (j - 1) * 2048, WHr + (j - 1) * 2048,
                BHr + (j - 1) * 2048, bv[j - 1], biasCur,
                AH[p ^ 1], AL[p ^ 1], nullptr, nullptr, nullptr);
            p ^= 1;
        }
        k_gemm<2, 1><<<dim3(14, 32), 256, 0, stream>>>(
            AH[p], AL[p], WT_H[0], WT_L[0],
            nullptr, nullptr, nullptr, nullptr, nullptr,
            nullptr, nullptr, lo0, hi0, BOX[bcur]);
        biasPrev = biasCur;
        bprev = bcur;
        xcur = xnxt;
    }
    // rec3 for the layer-4 path (BIAS[(3-1)&1] = BIAS[0]) + seed b20/out
    k_relu_rec<<<8, 256, 0, stream>>>(BOX[bprev], BIAS[0],
                                      WLr + 3 * 2048, WHr + 3 * 2048, BHr + 3 * 2048,
                                      b20, out, bv[4]);

    // ---- layer 4: 20-row chains (split-K partial path) ----
    k_skinny2<<<dim3(32, 8), 256, 0, stream>>>(W[4], 1,
        WLr + 3 * 2048, WHr + 3 * 2048, W[3], 2048, PPa);
    k_skinny2<<<dim3(32, 8), 256, 0, stream>>>(PPa, 0,
        WLr + 2 * 2048, WHr + 2 * 2048, W[2], 2048, PPb);
    k_skinny2<<<dim3(32, 8), 256, 0, stream>>>(PPb, 0,
        WLr + 1 * 2048, WHr + 1 * 2048, W[1], 2048, PPc);
    k_skinny2<<<dim3(13, 8), 256, 0, stream>>>(PPc, 0,
        WLr, WHr, W[0], 784, PPd);
    k_bias20<<<dim3(8, 20), 256, 0, stream>>>(W[4], PPa, PPb, PPc,
        WLr, WHr, BHr, bv[0], bv[1], bv[2], bv[3], X[xcur], b20, out);
    k_fbox20<<<20, 256, 0, stream>>>(PPd, b20, lo0, hi0, out);
}

// Round 15
// 757.960 us; speedup vs baseline: 1.1984x; 1.0333x over previous
//
#include <hip/hip_runtime.h>
#include <hip/hip_bf16.h>

// DeepPoly MLP verifier (784->2048x4->10).
// Round 20: dispatch diet (21 -> 16). r19's occupancy fixes gave -56us;
// residual accounting shows ~100us of launch/serialization gaps on the
// serial stream. Merges (grid-range decode, no inter-block deps):
//  - k_prep: norm + fboxes0 (inline normalization; drops dep on norm) +
//    all 3 transposes -> one 14084-block dispatch (saves 4).
//  - k_tail4: skinny#4 (PPc->PPd) + bias20 -> one 264-block dispatch
//    (both depend only on PPc; bias20 never reads PPd) (saves 1).
// GEMM kernels byte-identical to r15 (control group: 106.5us, FETCH
// 83MB, conflicts 0). Ledger unchanged: depth-2 counted-vmcnt + LDS
// swizzle (row>>1)&3 + T5 setprio + XCD block swizzle.

#define MEAN_C 0.1307f
#define STD_C  0.3081f

// ---- workspace offsets (floats), total ~108.2 MB ----
#define OFF_X0     0u
#define OFF_X1     2048u
#define OFF_L0     4096u       // 896 used (zero-padded)
#define OFF_H0     5120u
#define OFF_WL     6144u       // 4*2048 (rec j at +j*2048)
#define OFF_WH     14336u
#define OFF_BHR    22528u
#define OFF_BOXA   30720u      // 4096
#define OFF_BOXB   34816u
#define OFF_BIASA  38912u      // 4096
#define OFF_BIASB  43008u
#define OFF_B20    47104u      // 32
#define OFF_W0TH   47136u      // f16 [896][2048]  = 917504 float-slots
#define OFF_W0TL   964640u
#define OFF_W1TH   1882144u    // f16 [2048][2048] = 2097152 float-slots
#define OFF_W1TL   3979296u
#define OFF_W2TH   6076448u
#define OFF_W2TL   8173600u
#define OFF_AH0    10270752u   // f16 [4096][2048] = 4194304 float-slots
#define OFF_AL0    14465056u
#define OFF_AH1    18659360u
#define OFF_AL1    22853664u
// PP split-K partials alias into AH1 (free during layer 4): 4 x 327680 floats
#define OFF_PPA    18659360u
#define OFF_PPB    18987040u
#define OFF_PPC    19314720u
#define OFF_PPD    19642400u
// end 27047968 floats

typedef _Float16 half8 __attribute__((ext_vector_type(8)));
typedef float floatx4 __attribute__((ext_vector_type(4)));

__device__ __forceinline__ void gl2lds16(const void* g, void* l) {
    __builtin_amdgcn_global_load_lds(
        (const __attribute__((address_space(1))) unsigned int*)g,
        (__attribute__((address_space(3))) unsigned int*)l, 16, 0, 0);
}

__device__ __forceinline__ float blockReduce256(float v) {
    #pragma unroll
    for (int o = 32; o > 0; o >>= 1) v += __shfl_down(v, o, 64);
    __shared__ float sred[4];
    int w = threadIdx.x >> 6;
    if ((threadIdx.x & 63) == 0) sred[w] = v;
    __syncthreads();
    float r = 0.f;
    if (threadIdx.x == 0) r = sred[0] + sred[1] + sred[2] + sred[3];
    return r;
}

__device__ __forceinline__ float2 blockReduce256x2(float a, float b) {
    #pragma unroll
    for (int o = 32; o > 0; o >>= 1) {
        a += __shfl_down(a, o, 64);
        b += __shfl_down(b, o, 64);
    }
    __shared__ float sa[4], sb[4];
    int w = threadIdx.x >> 6;
    if ((threadIdx.x & 63) == 0) { sa[w] = a; sb[w] = b; }
    __syncthreads();
    float2 r = {0.f, 0.f};
    if (threadIdx.x == 0) {
        r.x = sa[0] + sa[1] + sa[2] + sa[3];
        r.y = sb[0] + sb[1] + sb[2] + sb[3];
    }
    return r;
}

// DeepPoly relu relaxation from bounds (h,l).
__device__ __forceinline__ void relu_rec_calc(float h, float l,
                                              float& vwl, float& vwh, float& vbh) {
    if (h <= 0.f)      { vwl = 0.f; vwh = 0.f; vbh = 0.f; }
    else if (l >= 0.f) { vwl = 1.f; vwh = 1.f; vbh = 0.f; }
    else {
        float d = h - l;
        vwh = h / d;
        vbh = -(l * h) / d;
        vwl = (l * l > h * h) ? 0.f : 1.f;
    }
}

// Merged prologue: norm (4 blocks) + layer-0 interval/forward matvec
// (4096 blocks, inline normalization) + 3 transpose-splits (1792+4096+4096).
// All branches read only raw inputs -> no intra-dispatch dependencies.
__global__ __launch_bounds__(256) void k_prep(
        const float* __restrict__ x, const float* __restrict__ lo,
        const float* __restrict__ hi,
        const float* __restrict__ W0, const float* __restrict__ b0,
        const float* __restrict__ W1, const float* __restrict__ W2,
        float* __restrict__ ws,
        _Float16* __restrict__ T0h, _Float16* __restrict__ T0l,
        _Float16* __restrict__ T1h, _Float16* __restrict__ T1l,
        _Float16* __restrict__ T2h, _Float16* __restrict__ T2l,
        float* __restrict__ box, float* __restrict__ xout) {
    __shared__ float s[32][33];
    int b = blockIdx.x, tid = threadIdx.x;
    if (b < 4) {
        int i = b * 256 + tid;
        if (i < 784) {
            ws[OFF_X0 + i] = (x[i]  - MEAN_C) / STD_C;
            ws[OFF_L0 + i] = (lo[i] - MEAN_C) / STD_C;
            ws[OFF_H0 + i] = (hi[i] - MEAN_C) / STD_C;
        } else if (i < 896) {
            ws[OFF_L0 + i] = 0.f;
            ws[OFF_H0 + i] = 0.f;
        }
    } else if (b < 4 + 4096) {
        // layer-0 interval matvec + forward matvec, inline normalization
        int r = b - 4;
        int srow = r & 2047;
        int is_high = r < 2048;
        const float* Wr = W0 + (size_t)srow * 784;
        float acc = 0.f, accx = 0.f;
        for (int c = tid; c < 784; c += 256) {
            float m  = Wr[c];
            float xl = (lo[c] - MEAN_C) / STD_C;
            float xh = (hi[c] - MEAN_C) / STD_C;
            float xv = (x[c]  - MEAN_C) / STD_C;
            if (is_high) acc += (m < 0.f) ? m * xl : m * xh;
            else         acc += (m < 0.f) ? m * xh : m * xl;
            accx += m * xv;
        }
        float2 rr = blockReduce256x2(acc, accx);
        if (tid == 0) {
            box[r] = rr.x + b0[srow];
            if (is_high) xout[r] = rr.y + b0[r];
        }
    } else {
        // transpose + f16 hi/lo split
        const float* W; int NC; _Float16 *Th, *Tl; int bb;
        if (b < 4 + 4096 + 1792)            { bb = b - 4100; W = W0; NC = 784;  Th = T0h; Tl = T0l; }
        else if (b < 4 + 4096 + 1792 + 4096){ bb = b - 5892; W = W1; NC = 2048; Th = T1h; Tl = T1l; }
        else                                { bb = b - 9988; W = W2; NC = 2048; Th = T2h; Tl = T2l; }
        int gx = (NC == 784) ? 28 : 64;
        int bx = bb % gx, by = bb / gx;
        int c = tid & 31, r0 = tid >> 5;
        #pragma unroll
        for (int rr = 0; rr < 4; rr++) {
            int k = by * 32 + r0 + rr * 8;
            int n = bx * 32 + c;
            float v = (n < NC) ? W[(size_t)k * NC + n] : 0.f;
            s[c][r0 + rr * 8] = v;
        }
        __syncthreads();
        #pragma unroll
        for (int rr = 0; rr < 4; rr++) {
            int nl = r0 + rr * 8;
            float v = s[nl][c];
            _Float16 h = (_Float16)v;
            size_t o = (size_t)(bx * 32 + nl) * 2048 + by * 32 + c;
            Th[o] = h;
            Tl[o] = (_Float16)(v - (float)h);
        }
    }
}

// First backsub step of layer i, with INLINE relu-record computation from
// (boxPrev, biasPrev): T_{i-1}(W_i) stacked (4096 rows) -> f16 hi/lo A;
// bias = bv_i + (bhr dot + T@b_{i-1}); block 0 materializes rec arrays;
// thread 0 zeroes boxOut[row]; rows<2048 also compute y = W_i@relu(x)+bv_i.
__global__ __launch_bounds__(256) void k_relu_split(
        const float* __restrict__ Wi, const float* __restrict__ xin,
        const float* __restrict__ boxPrev, const float* __restrict__ biasPrev,
        float* __restrict__ recWL, float* __restrict__ recWH, float* __restrict__ recBH,
        const float* __restrict__ bj, const float* __restrict__ bvi,
        float* __restrict__ bias, float* __restrict__ boxOut,
        float* __restrict__ xout,
        _Float16* __restrict__ Ahi, _Float16* __restrict__ Alo) {
    int row = blockIdx.x;
    int is_high = row < 2048;
    int srow = row & 2047;
    const float* src = Wi + (size_t)srow * 2048;
    int c0 = threadIdx.x * 8;
    float mv[8], bxh[8], bxl[8], abj[8], ax[8];
    *(float4*)&mv[0]  = *(const float4*)(src + c0);
    *(float4*)&mv[4]  = *(const float4*)(src + c0 + 4);
    *(float4*)&bxh[0] = *(const float4*)(boxPrev + c0);
    *(float4*)&bxh[4] = *(const float4*)(boxPrev + c0 + 4);
    *(float4*)&bxl[0] = *(const float4*)(boxPrev + 2048 + c0);
    *(float4*)&bxl[4] = *(const float4*)(boxPrev + 2048 + c0 + 4);
    *(float4*)&abj[0] = *(const float4*)(bj + c0);
    *(float4*)&abj[4] = *(const float4*)(bj + c0 + 4);
    *(float4*)&ax[0]  = *(const float4*)(xin + c0);
    *(float4*)&ax[4]  = *(const float4*)(xin + c0 + 4);
    if (biasPrev) {
        float ph[8], pl[8];
        *(float4*)&ph[0] = *(const float4*)(biasPrev + c0);
        *(float4*)&ph[4] = *(const float4*)(biasPrev + c0 + 4);
        *(float4*)&pl[0] = *(const float4*)(biasPrev + 2048 + c0);
        *(float4*)&pl[4] = *(const float4*)(biasPrev + 2048 + c0 + 4);
        #pragma unroll
        for (int e = 0; e < 8; e++) { bxh[e] += ph[e]; bxl[e] += pl[e]; }
    }
    float acc = 0.f, accx = 0.f;
    float rl[8], rh[8], rb[8];
    half8 hi, lo;
    #pragma unroll
    for (int e = 0; e < 8; e++) {
        relu_rec_calc(bxh[e], bxl[e], rl[e], rh[e], rb[e]);
        float m = mv[e];
        float t, bt;
        if (is_high) { t = (m > 0.f) ? m * rh[e] : m * rl[e]; bt = fmaxf(m, 0.f) * rb[e]; }
        else         { t = (m > 0.f) ? m * rl[e] : m * rh[e]; bt = fminf(m, 0.f) * rb[e]; }
        acc += bt + t * abj[e];
        accx += m * fmaxf(ax[e], 0.f);
        _Float16 h = (_Float16)t;
        hi[e] = h;
        lo[e] = (_Float16)(t - (float)h);
    }
    *(half8*)(Ahi + (size_t)row * 2048 + c0) = hi;
    *(half8*)(Alo + (size_t)row * 2048 + c0) = lo;
    if (row == 0) {   // materialize rec arrays for later consumers
        *(float4*)(recWL + c0) = *(float4*)&rl[0];
        *(float4*)(recWL + c0 + 4) = *(float4*)&rl[4];
        *(float4*)(recWH + c0) = *(float4*)&rh[0];
        *(float4*)(recWH + c0 + 4) = *(float4*)&rh[4];
        *(float4*)(recBH + c0) = *(float4*)&rb[0];
        *(float4*)(recBH + c0 + 4) = *(float4*)&rb[4];
    }
    float2 rr = blockReduce256x2(acc, accx);
    if (threadIdx.x == 0) {
        bias[row] = bvi[srow] + rr.x;
        boxOut[row] = 0.f;
        if (is_high) xout[row] = rr.y + bvi[row];
    }
}

// C[4096,NP] = (Ah+Al) @ (Bh+Bl)^T, 3 f16 products. BM=128, BN=NT*32,
// BK=32; 256 threads. Depth-2 counted-vmcnt pipeline (r9) + T5 setprio
// (r11) + XCD-aware block swizzle (r15). UNCHANGED from r15.
// EPI 0: relu-backsub epilogue (emit next Ah/Al + bias atomics).
// EPI 1: interval-matvec epilogue (atomics into pre-zeroed BOX).
template<int NT, int EPI>
__global__ __launch_bounds__(256, 2) void k_gemm(
        const _Float16* __restrict__ Ah, const _Float16* __restrict__ Al,
        const _Float16* __restrict__ Bh, const _Float16* __restrict__ Bl,
        const float* __restrict__ wl, const float* __restrict__ wh,
        const float* __restrict__ bhr, const float* __restrict__ bj,
        float* __restrict__ bias,
        _Float16* __restrict__ oAh, _Float16* __restrict__ oAl,
        const float* __restrict__ lo0, const float* __restrict__ hi0,
        float* __restrict__ box) {
    __shared__ _Float16 sAh[2][128 * 32], sAl[2][128 * 32];
    __shared__ _Float16 sBh[2][NT * 32 * 32], sBl[2][NT * 32 * 32];
    int tid = threadIdx.x;

    // XCD-aware swizzle: nwg (512 or 448) is divisible by 8 -> bijective.
    int gx = gridDim.x;
    int bid = blockIdx.y * gx + blockIdx.x;
    int cpx = (gx * gridDim.y) >> 3;
    int l   = (bid & 7) * cpx + (bid >> 3);
    int bx  = l % gx;
    int by  = l / gx;
    int row0 = by * 128, col0 = bx * (NT * 32);

    int cr = tid >> 2;
    int q  = (tid & 3) ^ ((cr >> 1) & 3);   // bank swizzle at fetch (keyed on row>>1)
    const _Float16* gAh0 = Ah + (size_t)(row0 + cr) * 2048 + q * 8;
    const _Float16* gAh1 = gAh0 + (size_t)64 * 2048;
    const _Float16* gAl0 = Al + (size_t)(row0 + cr) * 2048 + q * 8;
    const _Float16* gAl1 = gAl0 + (size_t)64 * 2048;
    const _Float16* gBh0 = Bh + (size_t)(col0 + cr) * 2048 + q * 8;
    const _Float16* gBl0 = Bl + (size_t)(col0 + cr) * 2048 + q * 8;
    const _Float16* gBh1 = gBh0 + (size_t)64 * 2048;   // NT==4 only
    const _Float16* gBl1 = gBl0 + (size_t)64 * 2048;
    int loff = tid * 8;

    int lane = tid & 63, wv = tid >> 6;
    int wm = wv & 1, wn = wv >> 1;
    int l15 = lane & 15, lq = lane >> 4;
    int soff = (lq ^ ((l15 >> 1) & 3)) * 8;  // matches write-side swizzle
    int arow = wm * 64 + l15;
    int brow = wn * (NT * 16) + l15;

    floatx4 acc[4][NT];
    floatx4 z = {0.f, 0.f, 0.f, 0.f};
    #pragma unroll
    for (int i = 0; i < 4; i++)
        #pragma unroll
        for (int j = 0; j < NT; j++) acc[i][j] = z;

    // per-wave loads per K-tile: NT==4 -> 8, NT==2 -> 6
    auto STAGE = [&](int b, int k0) {
        gl2lds16(gAh0 + k0, &sAh[b][loff]);
        gl2lds16(gAh1 + k0, &sAh[b][loff + 2048]);
        gl2lds16(gAl0 + k0, &sAl[b][loff]);
        gl2lds16(gAl1 + k0, &sAl[b][loff + 2048]);
        gl2lds16(gBh0 + k0, &sBh[b][loff]);
        gl2lds16(gBl0 + k0, &sBl[b][loff]);
        if (NT == 4) {
            gl2lds16(gBh1 + k0, &sBh[b][loff + 2048]);
            gl2lds16(gBl1 + k0, &sBl[b][loff + 2048]);
        }
    };

    STAGE(0, 0);
    STAGE(1, 32);
    if constexpr (NT == 4) asm volatile("s_waitcnt vmcnt(8)" ::: "memory");
    else                   asm volatile("s_waitcnt vmcnt(6)" ::: "memory");
    __builtin_amdgcn_s_barrier();
    __builtin_amdgcn_sched_barrier(0);

    for (int t = 0; t < 64; ++t) {
        int cur = t & 1;
        half8 bh[NT], bl[NT], ah4[4], al4[4];
        #pragma unroll
        for (int nt = 0; nt < NT; nt++) {
            bh[nt] = *(const half8*)&sBh[cur][(brow + nt * 16) * 32 + soff];
            bl[nt] = *(const half8*)&sBl[cur][(brow + nt * 16) * 32 + soff];
        }
        #pragma unroll
        for (int mt = 0; mt < 4; mt++) {
            ah4[mt] = *(const half8*)&sAh[cur][(arow + mt * 16) * 32 + soff];
            al4[mt] = *(const half8*)&sAl[cur][(arow + mt * 16) * 32 + soff];
        }
        // all reads of buf[cur] retired before anyone overwrites it
        asm volatile("s_waitcnt lgkmcnt(0)" ::: "memory");
        __builtin_amdgcn_sched_barrier(0);
        __builtin_amdgcn_s_barrier();
        __builtin_amdgcn_sched_barrier(0);
        if (t < 62) STAGE(cur, (t + 2) * 32);   // overwrite buf[cur] for t+2
        __builtin_amdgcn_s_setprio(1);
        #pragma unroll
        for (int mt = 0; mt < 4; mt++) {
            #pragma unroll
            for (int nt = 0; nt < NT; nt++) {
                acc[mt][nt] = __builtin_amdgcn_mfma_f32_16x16x32_f16(ah4[mt], bh[nt], acc[mt][nt], 0, 0, 0);
                acc[mt][nt] = __builtin_amdgcn_mfma_f32_16x16x32_f16(al4[mt], bh[nt], acc[mt][nt], 0, 0, 0);
                acc[mt][nt] = __builtin_amdgcn_mfma_f32_16x16x32_f16(ah4[mt], bl[nt], acc[mt][nt], 0, 0, 0);
            }
        }
        __builtin_amdgcn_s_setprio(0);
        if (t < 63) {
            if (t < 62) {   // wait tile t+1 only; t+2's loads stay in flight
                if constexpr (NT == 4) asm volatile("s_waitcnt vmcnt(8)" ::: "memory");
                else                   asm volatile("s_waitcnt vmcnt(6)" ::: "memory");
            } else {        // pipeline drain before the final tile
                asm volatile("s_waitcnt vmcnt(0)" ::: "memory");
            }
            __builtin_amdgcn_s_barrier();
            __builtin_amdgcn_sched_barrier(0);
        }
    }

    // C/D layout: col = lane&15, row = (lane>>4)*4 + reg
    int is_high = row0 < 2048;
    float bsum[4][4];
    #pragma unroll
    for (int mt = 0; mt < 4; mt++)
        #pragma unroll
        for (int r = 0; r < 4; r++) bsum[mt][r] = 0.f;

    #pragma unroll
    for (int nt = 0; nt < NT; nt++) {
        int gc = col0 + wn * (NT * 16) + nt * 16 + l15;
        if (EPI == 0) {
            float cwl = wl[gc], cwh = wh[gc], cbh = bhr[gc], cbj = bj[gc];
            #pragma unroll
            for (int mt = 0; mt < 4; mt++) {
                #pragma unroll
                for (int r = 0; r < 4; r++) {
                    float m = acc[mt][nt][r];
                    float t, bt;
                    if (is_high) { t = (m > 0.f) ? m * cwh : m * cwl; bt = fmaxf(m, 0.f) * cbh; }
                    else         { t = (m > 0.f) ? m * cwl : m * cwh; bt = fminf(m, 0.f) * cbh; }
                    bsum[mt][r] += bt + t * cbj;
                    int grow = row0 + wm * 64 + mt * 16 + lq * 4 + r;
                    size_t o = (size_t)grow * 2048 + gc;
                    _Float16 h = (_Float16)t;
                    oAh[o] = h;
                    oAl[o] = (_Float16)(t - (float)h);
                }
            }
        } else {
            float clo = lo0[gc], chi = hi0[gc];
            #pragma unroll
            for (int mt = 0; mt < 4; mt++) {
                #pragma unroll
                for (int r = 0; r < 4; r++) {
                    float m = acc[mt][nt][r];
                    float contrib;
                    if (is_high) contrib = (m < 0.f) ? m * clo : m * chi;
                    else         contrib = (m < 0.f) ? m * chi : m * clo;
                    bsum[mt][r] += contrib;
                }
            }
        }
    }
    #pragma unroll
    for (int mt = 0; mt < 4; mt++) {
        #pragma unroll
        for (int r = 0; r < 4; r++) {
            float v = bsum[mt][r];
            v += __shfl_xor(v, 1);
            v += __shfl_xor(v, 2);
            v += __shfl_xor(v, 4);
            v += __shfl_xor(v, 8);
            if (l15 == 0) {
                int grow = row0 + wm * 64 + mt * 16 + lq * 4 + r;
                if (EPI == 0) atomicAdd(&bias[grow], v);
                else          atomicAdd(&box[grow], v);
            }
        }
    }
}

// Rec3 capture + seed bias20/out with b4 for the atomic k_bias20 path.
__global__ void k_relu_rec(const float* __restrict__ box, const float* __restrict__ bias,
                           float* __restrict__ wl, float* __restrict__ wh,
                           float* __restrict__ bhr,
                           float* __restrict__ bias20, float* __restrict__ out,
                           const float* __restrict__ b4) {
    int i = blockIdx.x * blockDim.x + threadIdx.x;
    float h = box[i] + bias[i];
    float l = box[2048 + i] + bias[2048 + i];
    float vwl, vwh, vbh;
    relu_rec_calc(h, l, vwl, vwh, vbh);
    wl[i] = vwl; wh[i] = vwh; bhr[i] = vbh;
    if (blockIdx.x == 0) {
        int t = threadIdx.x;
        if (t < 20)      bias20[t] = b4[t % 10];   // base for atomic sums
        else if (t < 30) out[t - 20] = b4[t - 20]; // out[0..9] base
    }
}

// Layer-4 fused: reduce prev partials (or W4 bcast) + relu-backsub transform
// in prologue, then split-K skinny GEMM. Rows 0..9 high, 10..19 low.
// r19: 64-wide columns x 4-way K-half -> full-GPU grids.
__global__ __launch_bounds__(256) void k_skinny2(
        const float* __restrict__ src, int bcast,
        const float* __restrict__ wl, const float* __restrict__ wh,
        const float* __restrict__ W, int N, float* __restrict__ Ppart) {
    __shared__ float sA[20 * 256];
    __shared__ float sRed[20 * 192];
    int ky = blockIdx.y, k0 = ky * 256;
    int tid = threadIdx.x;
    for (int idx = tid; idx < 20 * 256; idx += 256) {
        int r = idx >> 8, c = idx & 255;
        int gc = k0 + c;
        float m;
        if (bcast) m = src[(size_t)(r % 10) * 2048 + gc];
        else {
            m = 0.f;
            #pragma unroll
            for (int p = 0; p < 8; p++)
                m += src[(size_t)p * 40960 + (size_t)r * 2048 + gc];
        }
        float t = (r < 10) ? ((m > 0.f) ? m * wh[gc] : m * wl[gc])
                           : ((m > 0.f) ? m * wl[gc] : m * wh[gc]);
        sA[idx] = t;
    }
    __syncthreads();
    int c = blockIdx.x * 64 + (tid & 63);
    int kh = tid >> 6;   // 0..3, each covers 64 of the 256 K-chunk
    float acc[20];
    #pragma unroll
    for (int r = 0; r < 20; r++) acc[r] = 0.f;
    if (c < N) {
        const float* Wp = W + (size_t)(k0 + kh * 64) * N + c;
        for (int kk = 0; kk < 64; kk++) {
            float w = Wp[(size_t)kk * N];
            #pragma unroll
            for (int r = 0; r < 20; r++) acc[r] += sA[r * 256 + kh * 64 + kk] * w;
        }
    }
    if (kh > 0 && c < N) {
        #pragma unroll
        for (int r = 0; r < 20; r++)
            sRed[r * 192 + (kh - 1) * 64 + (tid & 63)] = acc[r];
    }
    __syncthreads();
    if (kh == 0 && c < N) {
        #pragma unroll
        for (int r = 0; r < 20; r++)
            Ppart[(size_t)ky * 40960 + (size_t)r * 2048 + c] =
                acc[r] + sRed[r * 192 + (tid & 63)]
                       + sRed[r * 192 + 64 + (tid & 63)]
                       + sRed[r * 192 + 128 + (tid & 63)];
    }
}

// Merged tail: skinny#4 (PPc -> PPd over W0, 104 blocks) + bias20
// (160 blocks). Both depend only on PPc/PPa/PPb; neither reads the
// other's output. fbox20 follows and consumes both.
__global__ __launch_bounds__(256) void k_tail4(
        const float* __restrict__ PPcS, const float* __restrict__ W0, int N0,
        float* __restrict__ PPd,
        const float* __restrict__ W4,
        const float* __restrict__ PPa, const float* __restrict__ PPb,
        const float* __restrict__ WLr, const float* __restrict__ WHr,
        const float* __restrict__ BHr,
        const float* __restrict__ b0, const float* __restrict__ b1,
        const float* __restrict__ b2, const float* __restrict__ b3,
        const float* __restrict__ x3,
        float* __restrict__ bias20, float* __restrict__ out) {
    __shared__ float sA[20 * 256];
    __shared__ float sRed[20 * 192];
    int b = blockIdx.x, tid = threadIdx.x;
    if (b < 104) {
        // skinny#4: bx in [0,13), ky in [0,8); src = sum of PPc partials
        int bx = b % 13, ky = b / 13;
        int k0 = ky * 256;
        for (int idx = tid; idx < 20 * 256; idx += 256) {
            int r = idx >> 8, c = idx & 255;
            int gc = k0 + c;
            float m = 0.f;
            #pragma unroll
            for (int p = 0; p < 8; p++)
                m += PPcS[(size_t)p * 40960 + (size_t)r * 2048 + gc];
            float t = (r < 10) ? ((m > 0.f) ? m * WHr[gc] : m * WLr[gc])
                               : ((m > 0.f) ? m * WLr[gc] : m * WHr[gc]);
            sA[idx] = t;
        }
        __syncthreads();
        int c = bx * 64 + (tid & 63);
        int kh = tid >> 6;
        float acc[20];
        #pragma unroll
        for (int r = 0; r < 20; r++) acc[r] = 0.f;
        if (c < N0) {
            const float* Wp = W0 + (size_t)(k0 + kh * 64) * N0 + c;
            for (int kk = 0; kk < 64; kk++) {
                float w = Wp[(size_t)kk * N0];
                #pragma unroll
                for (int r = 0; r < 20; r++) acc[r] += sA[r * 256 + kh * 64 + kk] * w;
            }
        }
        if (kh > 0 && c < N0) {
            #pragma unroll
            for (int r = 0; r < 20; r++)
                sRed[r * 192 + (kh - 1) * 64 + (tid & 63)] = acc[r];
        }
        __syncthreads();
        if (kh == 0 && c < N0) {
            #pragma unroll
            for (int r = 0; r < 20; r++)
                PPd[(size_t)ky * 40960 + (size_t)r * 2048 + c] =
                    acc[r] + sRed[r * 192 + (tid & 63)]
                           + sRed[r * 192 + 64 + (tid & 63)]
                           + sRed[r * 192 + 128 + (tid & 63)];
        }
    } else {
        // bias20: 160 blocks = 8 c-chunks x 20 rows
        int bb = b - 104;
        int row = bb >> 3, cx = bb & 7;
        int is_high = row < 10;
        int srow = row % 10;
        int c = cx * 256 + tid;
        float acc = 0.f, accx = 0.f;
        {   // rec3 on W4 (+ forward matvec with relu'd x3)
            float m = W4[(size_t)srow * 2048 + c];
            float wlv = WLr[3 * 2048 + c], whv = WHr[3 * 2048 + c], bhv = BHr[3 * 2048 + c];
            float t  = is_high ? ((m > 0.f) ? m * whv : m * wlv) : ((m > 0.f) ? m * wlv : m * whv);
            float bt = is_high ? fmaxf(m, 0.f) * bhv : fminf(m, 0.f) * bhv;
            acc += bt + t * b3[c];
            accx += m * fmaxf(x3[c], 0.f);
        }
        {   // rec2 on sum PPa
            float m = 0.f;
            #pragma unroll
            for (int p = 0; p < 8; p++) m += PPa[(size_t)p * 40960 + (size_t)row * 2048 + c];
            float wlv = WLr[2 * 2048 + c], whv = WHr[2 * 2048 + c], bhv = BHr[2 * 2048 + c];
            float t  = is_high ? ((m > 0.f) ? m * whv : m * wlv) : ((m > 0.f) ? m * wlv : m * whv);
            float bt = is_high ? fmaxf(m, 0.f) * bhv : fminf(m, 0.f) * bhv;
            acc += bt + t * b2[c];
        }
        {   // rec1 on sum PPb
            float m = 0.f;
            #pragma unroll
            for (int p = 0; p < 8; p++) m += PPb[(size_t)p * 40960 + (size_t)row * 2048 + c];
            float wlv = WLr[1 * 2048 + c], whv = WHr[1 * 2048 + c], bhv = BHr[1 * 2048 + c];
            float t  = is_high ? ((m > 0.f) ? m * whv : m * wlv) : ((m > 0.f) ? m * wlv : m * whv);
            float bt = is_high ? fmaxf(m, 0.f) * bhv : fminf(m, 0.f) * bhv;
            acc += bt + t * b1[c];
        }
        {   // rec0 on sum PPc
            float m = 0.f;
            #pragma unroll
            for (int p = 0; p < 8; p++) m += PPcS[(size_t)p * 40960 + (size_t)row * 2048 + c];
            float wlv = WLr[c], whv = WHr[c], bhv = BHr[c];
            float t  = is_high ? ((m > 0.f) ? m * whv : m * wlv) : ((m > 0.f) ? m * wlv : m * whv);
            float bt = is_high ? fmaxf(m, 0.f) * bhv : fminf(m, 0.f) * bhv;
            acc += bt + t * b0[c];
        }
        float2 rr = blockReduce256x2(acc, accx);
        if (tid == 0) {
            atomicAdd(&bias20[row], rr.x);
            if (is_high) atomicAdd(&out[row], rr.y);
        }
    }
}

// Final layer-4 interval matvec from 8 split-K parts.
__global__ void k_fbox20(const float* __restrict__ Ppart,
                         const float* __restrict__ bias20,
                         const float* __restrict__ lo0, const float* __restrict__ hi0,
                         float* __restrict__ out) {
    int row = blockIdx.x;
    int is_high = row < 10;
    float acc = 0.f;
    for (int c = threadIdx.x; c < 784; c += 256) {
        float m = 0.f;
        #pragma unroll
        for (int p = 0; p < 8; p++)
            m += Ppart[(size_t)p * 40960 + (size_t)row * 2048 + c];
        if (is_high) acc += (m < 0.f) ? m * lo0[c] : m * hi0[c];
        else         acc += (m < 0.f) ? m * hi0[c] : m * lo0[c];
    }
    acc = blockReduce256(acc);
    if (threadIdx.x == 0) {
        float v = acc + bias20[row];
        out[is_high ? (20 + row) : row] = v;
    }
}

extern "C" void kernel_launch(void* const* d_in, const int* in_sizes, int n_in,
                              void* d_out, int out_size, void* d_ws, size_t ws_size,
                              hipStream_t stream) {
    const float* x_in  = (const float*)d_in[0];
    const float* lo_in = (const float*)d_in[1];
    const float* hi_in = (const float*)d_in[2];
    const float* W[5];
    const float* bv[5];
    for (int i = 0; i < 5; i++) {
        W[i]  = (const float*)d_in[3 + 2 * i];
        bv[i] = (const float*)d_in[4 + 2 * i];
    }
    float* ws = (float*)d_ws;
    float* out = (float*)d_out;

    float* X[2]    = {ws + OFF_X0, ws + OFF_X1};
    float* lo0     = ws + OFF_L0;
    float* hi0     = ws + OFF_H0;
    float* BOX[2]  = {ws + OFF_BOXA, ws + OFF_BOXB};
    float* BIAS[2] = {ws + OFF_BIASA, ws + OFF_BIASB};
    float* b20     = ws + OFF_B20;
    float* PPa     = ws + OFF_PPA;
    float* PPb     = ws + OFF_PPB;
    float* PPc     = ws + OFF_PPC;
    float* PPd     = ws + OFF_PPD;
    _Float16* WT_H[3] = {(_Float16*)(ws + OFF_W0TH), (_Float16*)(ws + OFF_W1TH),
                         (_Float16*)(ws + OFF_W2TH)};
    _Float16* WT_L[3] = {(_Float16*)(ws + OFF_W0TL), (_Float16*)(ws + OFF_W1TL),
                         (_Float16*)(ws + OFF_W2TL)};
    _Float16* AH[2] = {(_Float16*)(ws + OFF_AH0), (_Float16*)(ws + OFF_AH1)};
    _Float16* AL[2] = {(_Float16*)(ws + OFF_AL0), (_Float16*)(ws + OFF_AL1)};
    float* WLr = ws + OFF_WL;
    float* WHr = ws + OFF_WH;
    float* BHr = ws + OFF_BHR;

    // ---- merged prologue: norm + layer-0 boxes + 3 transposes ----
    k_prep<<<14084, 256, 0, stream>>>(
        x_in, lo_in, hi_in, W[0], bv[0], W[1], W[2], ws,
        WT_H[0], WT_L[0], WT_H[1], WT_L[1], WT_H[2], WT_L[2],
        BOX[0], X[1]);

    // ---- layers 1..3 ----
    int xcur = 1, bprev = 0;   // BOX[bprev] = prev layer bounds; bias ping-pong
    const float* biasPrev = nullptr;
    for (int i = 1; i <= 3; i++) {
        int xnxt = xcur ^ 1;
        int bcur = bprev ^ 1;
        float* biasCur = BIAS[(i - 1) & 1];
        k_relu_split<<<4096, 256, 0, stream>>>(
            W[i], X[xcur], BOX[bprev], biasPrev,
            WLr + (i - 1) * 2048, WHr + (i - 1) * 2048, BHr + (i - 1) * 2048,
            bv[i - 1], bv[i], biasCur, BOX[bcur], X[xnxt], AH[0], AL[0]);
        int p = 0;
        for (int j = i - 1; j >= 1; j--) {
            k_gemm<4, 0><<<dim3(16, 32), 256, 0, stream>>>(
                AH[p], AL[p], WT_H[j], WT_L[j],
                WLr + (j - 1) * 2048, WHr + (j - 1) * 2048,
                BHr + (j - 1) * 2048, bv[j - 1], biasCur,
                AH[p ^ 1], AL[p ^ 1], nullptr, nullptr, nullptr);
            p ^= 1;
        }
        k_gemm<2, 1><<<dim3(14, 32), 256, 0, stream>>>(
            AH[p], AL[p], WT_H[0], WT_L[0],
            nullptr, nullptr, nullptr, nullptr, nullptr,
            nullptr, nullptr, lo0, hi0, BOX[bcur]);
        biasPrev = biasCur;
        bprev = bcur;
        xcur = xnxt;
    }
    // rec3 for the layer-4 path (BIAS[(3-1)&1] = BIAS[0]) + seed b20/out
    k_relu_rec<<<8, 256, 0, stream>>>(BOX[bprev], BIAS[0],
                                      WLr + 3 * 2048, WHr + 3 * 2048, BHr + 3 * 2048,
                                      b20, out, bv[4]);

    // ---- layer 4: 20-row chains (split-K partial path) ----
    k_skinny2<<<dim3(32, 8), 256, 0, stream>>>(W[4], 1,
        WLr + 3 * 2048, WHr + 3 * 2048, W[3], 2048, PPa);
    k_skinny2<<<dim3(32, 8), 256, 0, stream>>>(PPa, 0,
        WLr + 2 * 2048, WHr + 2 * 2048, W[2], 2048, PPb);
    k_skinny2<<<dim3(32, 8), 256, 0, stream>>>(PPb, 0,
        WLr + 1 * 2048, WHr + 1 * 2048, W[1], 2048, PPc);
    // merged: skinny#4 (PPc->PPd over W0) + bias20 atomics
    k_tail4<<<264, 256, 0, stream>>>(PPc, W[0], 784, PPd,
        W[4], PPa, PPb, WLr, WHr, BHr,
        bv[0], bv[1], bv[2], bv[3], X[xcur], b20, out);
    k_fbox20<<<20, 256, 0, stream>>>(PPd, b20, lo0, hi0, out);
}